// Round 12
// baseline (257.691 us; speedup 1.0000x reference)
//
#include <hip/hip_runtime.h>
#include <stdint.h>

#define BS 4
#define SEQ 1024
#define DIM 1024
#define NH 16
#define DH 64
#define MROWS (BS*SEQ)   // 4096

#define MT 128
#define NT 128
#define KT 32
#define NBM (MROWS/MT)   // 32
#define NBN (DIM/NT)     // 8
#define NWG (NBM*NBN)    // 256
#define NKT (DIM/KT)     // 32

#define NROWS (BS*NH*SEQ)        // 65536 (b,h,q) rows
#define OPART_ELEMS ((size_t)NROWS*DH)   // 4,194,304 per split

typedef __attribute__((ext_vector_type(8))) short bf16x8;
typedef __attribute__((ext_vector_type(4))) float f32x4;
typedef __attribute__((ext_vector_type(8))) unsigned short ushort8;
typedef __attribute__((ext_vector_type(4))) float float4v;
typedef __attribute__((ext_vector_type(4))) int int4v;
typedef __attribute__((ext_vector_type(2))) unsigned int uint32x2;

__device__ __forceinline__ unsigned short f2bf(float x) {
  union { float f; uint32_t u; } a; a.f = x;
  uint32_t r = (a.u + 0x7FFFu + ((a.u >> 16) & 1u)) >> 16;  // RNE
  return (unsigned short)r;
}

__device__ __forceinline__ float bf2f(unsigned short u) {
  union { uint32_t u; float f; } a; a.u = ((uint32_t)u) << 16;
  return a.f;
}

// packed f32x2 -> bf16x2 (lo = first arg); no builtin on gfx950 -> inline asm (T12)
__device__ __forceinline__ uint32_t cvtpk_bf16(float lo, float hi) {
  uint32_t d;
  asm("v_cvt_pk_bf16_f32 %0, %1, %2" : "=v"(d) : "v"(lo), "v"(hi));
  return d;
}

// raw 2^x (softmax runs in log2 domain; log2e folded into Q scale upstream)
__device__ __forceinline__ float exp2a(float x) {
  float r;
  asm("v_exp_f32 %0, %1" : "=v"(r) : "v"(x));
  return r;
}

typedef const void __attribute__((address_space(1)))* gvp;
typedef void __attribute__((address_space(3)))* lvp;
__device__ __forceinline__ void gld_lds16(const void* g, void* l) {
  // async global->LDS, 16B/lane; LDS dest = wave-uniform base + lane*16
  __builtin_amdgcn_global_load_lds((gvp)g, (lvp)l, 16, 0, 0);
}

// ---------------- fp32 -> bf16 cast (query/key/value) ----------------
__global__ __launch_bounds__(256) void cast_qkv(
    const float* __restrict__ q, const float* __restrict__ k, const float* __restrict__ v,
    unsigned short* __restrict__ qo, unsigned short* __restrict__ ko, unsigned short* __restrict__ vo) {
  const float* s = blockIdx.y == 0 ? q : (blockIdx.y == 1 ? k : v);
  unsigned short* d = blockIdx.y == 0 ? qo : (blockIdx.y == 1 ? ko : vo);
  size_t i = ((size_t)blockIdx.x * 256 + threadIdx.x) * 8;
  float4v x0 = *(const float4v*)(s + i);
  float4v x1 = *(const float4v*)(s + i + 4);
  ushort8 r;
  r[0]=f2bf(x0[0]); r[1]=f2bf(x0[1]); r[2]=f2bf(x0[2]); r[3]=f2bf(x0[3]);
  r[4]=f2bf(x1[0]); r[5]=f2bf(x1[1]); r[6]=f2bf(x1[2]); r[7]=f2bf(x1[3]);
  *(ushort8*)(d + i) = r;
}

// ---------------- mask-folded gauss table: gw[b][s] = mask ? gauss+1e-10 : 0 ----------------
__global__ __launch_bounds__(256) void gw_prep(
    const float* __restrict__ gauss, const int* __restrict__ mask, float* __restrict__ gw) {
  int i = blockIdx.x * 256 + threadIdx.x;
  gw[i] = mask[i] ? gauss[i] + 1e-10f : 0.f;
}

// ---------------- weight cast + transpose: WT[n][k] = bf16(W[k][n]) ----------------
__global__ __launch_bounds__(256) void wcast_t(
    const float* __restrict__ w0, const float* __restrict__ w1,
    const float* __restrict__ w2, const float* __restrict__ w3,
    unsigned short* __restrict__ t0, unsigned short* __restrict__ t1,
    unsigned short* __restrict__ t2, unsigned short* __restrict__ t3) {
  __shared__ float tile[32][33];
  const float* W = blockIdx.z == 0 ? w0 : blockIdx.z == 1 ? w1 : blockIdx.z == 2 ? w2 : w3;
  unsigned short* T = blockIdx.z == 0 ? t0 : blockIdx.z == 1 ? t1 : blockIdx.z == 2 ? t2 : t3;
  int tx = threadIdx.x & 31, ty = threadIdx.x >> 5;   // 32 x 8
  int bx = blockIdx.x, by = blockIdx.y;
#pragma unroll
  for (int j = 0; j < 4; j++)
    tile[ty + 8*j][tx] = W[(size_t)(by*32 + ty + 8*j)*DIM + bx*32 + tx];
  __syncthreads();
#pragma unroll
  for (int j = 0; j < 4; j++)
    T[(size_t)(bx*32 + ty + 8*j)*DIM + by*32 + tx] = f2bf(tile[tx][ty + 8*j]);
}

// ---------------- GEMM core: m97-exact 128x128 tile ----------------
// 4 waves (2x2), each computes a 64x64 sub-tile: acc[4][4], 16 MFMA/K-step.
// MODE 0: bf16 out, (acc+bias)*scale; MODE 2: bf16, per-head transposed
// VT[b][h][d][s]; MODE 3: f32 out.
template<int MODE>
__device__ __forceinline__ void gemm_core(
    unsigned short* lds,
    const unsigned short* __restrict__ A, const unsigned short* __restrict__ BT,
    const float* __restrict__ bias, void* __restrict__ outp, float scale) {
  unsigned short* Abase = lds;                 // 2 x MT*KT
  unsigned short* Bbase = lds + 2*MT*KT;       // 2 x NT*KT
  int id = blockIdx.x;
  int sw = (id & 7) * (NWG/8) + (id >> 3);     // XCD swizzle (bijective, 256%8==0)
  int bn = sw & (NBN-1), bm = sw >> 3;         // bn-fast: XCD holds 1MB A-panel + 2MB B (<L2)
  int tid = threadIdx.x, w = tid >> 6, l = tid & 63;
  int wr = w >> 1, wc = w & 1;
  int lr = l & 15, lg = l >> 4;

  auto stage = [&](int buf, int kt) {
    const unsigned short* a0 = A + (size_t)(bm*MT + w*32 + (l>>2))*DIM + kt*KT + (l&3)*8;
    gld_lds16(a0,          Abase + buf*MT*KT + (w*32)*KT);
    gld_lds16(a0 + 16*DIM, Abase + buf*MT*KT + (w*32 + 16)*KT);
    const unsigned short* b0 = BT + (size_t)(bn*NT + w*32 + (l>>2))*DIM + kt*KT + (l&3)*8;
    gld_lds16(b0,          Bbase + buf*NT*KT + (w*32)*KT);
    gld_lds16(b0 + 16*DIM, Bbase + buf*NT*KT + (w*32 + 16)*KT);
  };

  f32x4 acc[4][4] = {};
  int buf = 0;
  stage(0, 0);
  __syncthreads();
  for (int kt = 0; kt < NKT; kt++) {
    if (kt + 1 < NKT) stage(buf ^ 1, kt + 1);
    unsigned short* As = Abase + buf*MT*KT;
    unsigned short* Bs = Bbase + buf*NT*KT;
    bf16x8 af[4], bf_[4];
#pragma unroll
    for (int mi = 0; mi < 4; mi++)
      af[mi] = *(const bf16x8*)&As[(wr*64 + mi*16 + lr)*KT + lg*8];
#pragma unroll
    for (int ni = 0; ni < 4; ni++)
      bf_[ni] = *(const bf16x8*)&Bs[(wc*64 + ni*16 + lr)*KT + lg*8];
#pragma unroll
    for (int mi = 0; mi < 4; mi++)
#pragma unroll
      for (int ni = 0; ni < 4; ni++)
        acc[mi][ni] = __builtin_amdgcn_mfma_f32_16x16x32_bf16(af[mi], bf_[ni], acc[mi][ni], 0, 0, 0);
    __syncthreads();   // drains vmcnt for the staged next tile + protects buffer reuse
    buf ^= 1;
  }

  int row0 = bm*MT + wr*64;
  int col0 = bn*NT + wc*64;
#pragma unroll
  for (int ni = 0; ni < 4; ni++) {
    int col = col0 + ni*16 + lr;
    float bv = bias[col];
#pragma unroll
    for (int mi = 0; mi < 4; mi++)
#pragma unroll
      for (int r = 0; r < 4; r++) {
        int row = row0 + mi*16 + lg*4 + r;
        float val = acc[mi][ni][r] + bv;
        if (MODE == 0) {
          ((unsigned short*)outp)[(size_t)row*DIM + col] = f2bf(val * scale);
        } else if (MODE == 2) {
          int b = row >> 10, s = row & 1023, h = col >> 6, d = col & 63;
          ((unsigned short*)outp)[(size_t)((b*NH + h)*DH + d)*SEQ + s] = f2bf(val);
        } else {
          ((float*)outp)[(size_t)row*DIM + col] = val;
        }
      }
  }
}

__global__ __launch_bounds__(256) void qkv_gemm(
    const unsigned short* __restrict__ qb, const unsigned short* __restrict__ kb,
    const unsigned short* __restrict__ vb,
    const unsigned short* __restrict__ WqT, const unsigned short* __restrict__ WkT,
    const unsigned short* __restrict__ WvT,
    const float* __restrict__ bq, const float* __restrict__ bk, const float* __restrict__ bv,
    unsigned short* __restrict__ Qp, unsigned short* __restrict__ Kp,
    unsigned short* __restrict__ VT) {
  __shared__ __align__(16) unsigned short lds[2*(MT+NT)*KT];
  int z = blockIdx.y;
  // Q scale = 1/sqrt(64) * log2(e): softmax runs in exp2 domain downstream
  if (z == 0)      gemm_core<0>(lds, qb, WqT, bq, Qp, 0.18033688011112042f);
  else if (z == 1) gemm_core<0>(lds, kb, WkT, bk, Kp, 1.0f);
  else             gemm_core<2>(lds, vb, WvT, bv, VT, 1.0f);
}

__global__ __launch_bounds__(256) void out_gemm(
    const unsigned short* __restrict__ ctx, const unsigned short* __restrict__ WoT,
    const float* __restrict__ bo, float* __restrict__ out) {
  __shared__ __align__(16) unsigned short lds[2*(MT+NT)*KT];
  gemm_core<3>(lds, ctx, WoT, bo, out, 1.0f);
}

// ---------------- flash attention, split-KV partial pass ----------------
// R10 diagnosis refined by R11: latency-chain-bound (VALUBusy 22%, MfmaUtil 9%,
// chain ~2700cyc/iter at only 4 resident waves/SIMD) and occupancy is GRID-capped
// (4096 q-waves = 16/CU max). Split-KV doubles waves: each block = 4 waves x 16
// q-rows processing HALF the keys (512, 8 iters of KVBLK=64), writing raw
// (unnormalized) partial O as bf16 + per-q-row (m,l) f32. gwl LDS copy dropped
// (gw read direct, 16KB L2-hot) -> LDS 25.2KB -> 6 blocks/CU = 24 waves/CU.
// Mechanics identical to R10 (proven): K global_load_lds dbuf + XOR swizzle,
// swapped QK^T, per-lane scalar softmax in exp2 domain, T13 defer-max, wave-
// local P slab, plain compiler-scheduled V loads.
__global__ __launch_bounds__(256, 6) void attn_part(
    const unsigned short* __restrict__ Qp, const unsigned short* __restrict__ Kp,
    const unsigned short* __restrict__ VT, const float* __restrict__ gw,
    unsigned short* __restrict__ Op, float* __restrict__ ml) {
  __shared__ __align__(16) unsigned short Klds[2*64*64];  // 16KB double-buffered K tile
  __shared__ __align__(16) unsigned short P[4][16][72];   // per-wave slab, padded
  int blk = blockIdx.x;
  int bh = blk & 63;                       // head-major: head bh pinned per XCD
  int rest = blk >> 6;                     // 0..31
  int qt = rest & 15, split = rest >> 4;   // split in {0,1}
  int b = bh >> 4, h = bh & 15;
  int tid = threadIdx.x, w = tid >> 6, l = tid & 63;
  int lr = l & 15, lg = l >> 4;
  int q0 = qt*64 + w*16;
  int kbase = split*512;

  const unsigned short* Qb = Qp + (size_t)(b*SEQ + q0 + lr)*DIM + h*DH + lg*8;
  bf16x8 aq0 = *(const bf16x8*)Qb;
  bf16x8 aq1 = *(const bf16x8*)(Qb + 32);

  float m_ = -1e30f, l_ = 0.f;             // per-lane scalars (q = lr), log2 domain
  f32x4 cacc[4] = {};                      // O^T[d = dt*16+lg*4+r][q = lr], unnormalized

  const unsigned short* Krow0 = Kp + (size_t)(b*SEQ)*DIM + h*DH;
  const unsigned short* Vb0   = VT + (size_t)((b*NH + h)*DH + lr)*SEQ + lg*8;
  const float* gwb = gw + b*SEQ;

  // staging geometry: lane l covers row (l>>3), 16B slot (l&7); source pre-swizzled by row&7
  int srow = l >> 3;
  int scol = ((l & 7) ^ srow) * 8;
  auto stageK = [&](int buf, int key0) {
    gld_lds16(Krow0 + (size_t)(key0 + w*16 +     srow)*DIM + scol, Klds + buf*64*64 + (w*16    )*64);
    gld_lds16(Krow0 + (size_t)(key0 + w*16 + 8 + srow)*DIM + scol, Klds + buf*64*64 + (w*16 + 8)*64);
  };

  stageK(0, kbase);
  __syncthreads();   // K[0] ready
  int buf = 0;
  for (int kt = 0; kt < 8; kt++) {
    int key0 = kbase + kt*64;
    // ---- issue next-K stage (async DMA, zero VGPR; wrapped -> unconditional) ----
    stageK(buf ^ 1, kbase + ((kt+1) & 7)*64);
    // ---- S^T = mfma(K, Q) from LDS (swizzled read): sa[nf][r] = S[key][q=lr] ----
    const unsigned short* Kt = Klds + buf*64*64;
    f32x4 sa[4] = {};
#pragma unroll
    for (int nf = 0; nf < 4; nf++) {
      int r1 = nf*16 + lr;
      int rx = r1 & 7;
      bf16x8 k0 = *(const bf16x8*)&Kt[r1*64 + ((lg       ^ rx) * 8)];
      bf16x8 k1 = *(const bf16x8*)&Kt[r1*64 + (((lg + 4) ^ rx) * 8)];
      sa[nf] = __builtin_amdgcn_mfma_f32_16x16x32_bf16(k0, aq0, sa[nf], 0, 0, 0);
      sa[nf] = __builtin_amdgcn_mfma_f32_16x16x32_bf16(k1, aq1, sa[nf], 0, 0, 0);
    }
    // ---- V loads (plain, compiler-scheduled) ----
    bf16x8 vf[4][2];
#pragma unroll
    for (int dt = 0; dt < 4; dt++) {
      vf[dt][0] = *(const bf16x8*)(Vb0 + (size_t)(dt*16)*SEQ + key0);
      vf[dt][1] = *(const bf16x8*)(Vb0 + (size_t)(dt*16)*SEQ + key0 + 32);
    }
    // ---- online softmax in exp2 domain; tree max; T13 defer-max ----
    float t0 = fmaxf(fmaxf(sa[0][0], sa[0][1]), fmaxf(sa[0][2], sa[0][3]));
    float t1 = fmaxf(fmaxf(sa[1][0], sa[1][1]), fmaxf(sa[1][2], sa[1][3]));
    float t2 = fmaxf(fmaxf(sa[2][0], sa[2][1]), fmaxf(sa[2][2], sa[2][3]));
    float t3 = fmaxf(fmaxf(sa[3][0], sa[3][1]), fmaxf(sa[3][2], sa[3][3]));
    float mx = fmaxf(fmaxf(t0, t1), fmaxf(t2, t3));
    mx = fmaxf(mx, __shfl_xor(mx, 16));
    mx = fmaxf(mx, __shfl_xor(mx, 32));
    if (!__all(mx - m_ <= 8.0f)) {         // rescale only on real max growth
      float mn = fmaxf(m_, mx);
      float alpha = exp2a(m_ - mn);
      m_ = mn;
      l_ *= alpha;
#pragma unroll
      for (int dt = 0; dt < 4; dt++)
#pragma unroll
        for (int r = 0; r < 4; r++) cacc[dt][r] *= alpha;
    }
    float rsn[4];
    uint32_t u[4][2];
#pragma unroll
    for (int nf = 0; nf < 4; nf++) {
      float4v g = *(const float4v*)&gwb[key0 + nf*16 + lg*4];   // L2-hot table
      float p0 = exp2a(sa[nf][0] - m_) * g[0];
      float p1 = exp2a(sa[nf][1] - m_) * g[1];
      float p2 = exp2a(sa[nf][2] - m_) * g[2];
      float p3 = exp2a(sa[nf][3] - m_) * g[3];
      rsn[nf] = (p0 + p1) + (p2 + p3);
      u[nf][0] = cvtpk_bf16(p0, p1);
      u[nf][1] = cvtpk_bf16(p2, p3);
    }
    float rs = (rsn[0] + rsn[1]) + (rsn[2] + rsn[3]);
    rs += __shfl_xor(rs, 16);
    rs += __shfl_xor(rs, 32);
    l_ += rs;
    // ---- P[q=lr][key]: 4x ds_write_b64 into wave-local slab ----
#pragma unroll
    for (int nf = 0; nf < 4; nf++) {
      uint32x2 uu; uu[0] = u[nf][0]; uu[1] = u[nf][1];
      *(uint32x2*)&P[w][lr][nf*16 + lg*4] = uu;
    }
    bf16x8 ap0 = *(const bf16x8*)&P[w][lr][lg*8];        // B-frag: keys 0..31
    bf16x8 ap1 = *(const bf16x8*)&P[w][lr][32 + lg*8];   // B-frag: keys 32..63
    // ---- O^T += mfma(V^T, P) ----
#pragma unroll
    for (int dt = 0; dt < 4; dt++) {
      cacc[dt] = __builtin_amdgcn_mfma_f32_16x16x32_bf16(vf[dt][0], ap0, cacc[dt], 0, 0, 0);
      cacc[dt] = __builtin_amdgcn_mfma_f32_16x16x32_bf16(vf[dt][1], ap1, cacc[dt], 0, 0, 0);
    }
    __syncthreads();   // K dbuf swap: waves done reading K[t]; next-K stage drains here
    buf ^= 1;
  }

  // ---- epilogue: write RAW partial O (bf16) + (m,l) per q-row ----
  int bhq = (bh << 10) + q0 + lr;          // (b*16+h)*1024 + q
  unsigned short* Orow = Op + (size_t)split*OPART_ELEMS + (size_t)bhq*DH;
#pragma unroll
  for (int dt = 0; dt < 4; dt++) {
    uint32x2 e;
    e[0] = cvtpk_bf16(cacc[dt][0], cacc[dt][1]);
    e[1] = cvtpk_bf16(cacc[dt][2], cacc[dt][3]);
    *(uint32x2*)&Orow[dt*16 + lg*4] = e;
  }
  if (lg == 0) {                           // lanes with same lr share m_,l_
    size_t mi = ((size_t)split*NROWS + bhq) * 2;
    ml[mi]     = m_;
    ml[mi + 1] = l_;
  }
}

// ---------------- split-KV combine: ctx = (O1*a1 + O2*a2) / (l1*a1 + l2*a2) ----------------
// 524288 threads: thread -> (bhq = t>>3, 8 d-elems). Pure memory pass (~25MB).
__global__ __launch_bounds__(256) void attn_reduce(
    const unsigned short* __restrict__ Op, const float* __restrict__ ml,
    unsigned short* __restrict__ ctx) {
  int t = blockIdx.x * 256 + threadIdx.x;
  int bhq = t >> 3;
  int d0 = (t & 7) * 8;
  float m1 = ml[(size_t)bhq*2],            l1 = ml[(size_t)bhq*2 + 1];
  float m2 = ml[((size_t)NROWS + bhq)*2],  l2 = ml[((size_t)NROWS + bhq)*2 + 1];
  float m  = fmaxf(m1, m2);
  float a1 = exp2a(m1 - m), a2 = exp2a(m2 - m);
  float lt = l1*a1 + l2*a2;
  float inv = lt > 0.f ? 1.f / lt : 0.f;
  float w1 = a1 * inv, w2 = a2 * inv;
  ushort8 o1 = *(const ushort8*)&Op[(size_t)bhq*DH + d0];
  ushort8 o2 = *(const ushort8*)&Op[OPART_ELEMS + (size_t)bhq*DH + d0];
  int b = bhq >> 14, h = (bhq >> 10) & 15, q = bhq & 1023;
  unsigned short* dst = ctx + ((size_t)(b*SEQ + q))*DIM + h*DH + d0;
  ushort8 r;
#pragma unroll
  for (int j = 0; j < 8; j++)
    r[j] = f2bf(bf2f(o1[j])*w1 + bf2f(o2[j])*w2);
  *(ushort8*)dst = r;
}

// ---------------- launch ----------------
extern "C" void kernel_launch(void* const* d_in, const int* in_sizes, int n_in,
                              void* d_out, int out_size, void* d_ws, size_t ws_size,
                              hipStream_t stream) {
  const float* query = (const float*)d_in[0];
  const float* key   = (const float*)d_in[1];
  const float* value = (const float*)d_in[2];
  const int*   mask  = (const int*)d_in[3];
  const float* gauss = (const float*)d_in[4];
  const float* Wq = (const float*)d_in[5];
  const float* bq = (const float*)d_in[6];
  const float* Wk = (const float*)d_in[7];
  const float* bk = (const float*)d_in[8];
  const float* Wv = (const float*)d_in[9];
  const float* bv = (const float*)d_in[10];
  const float* Wo = (const float*)d_in[11];
  const float* bo = (const float*)d_in[12];

  char* ws = (char*)d_ws;
  const size_t MB = 1024*1024;
  unsigned short* qb  = (unsigned short*)(ws + 0*MB);   // bf16 casts of inputs (8MB each)
  unsigned short* kb  = (unsigned short*)(ws + 8*MB);
  unsigned short* vb  = (unsigned short*)(ws + 16*MB);
  unsigned short* WqT = (unsigned short*)(ws + 24*MB);  // transposed bf16 weights (2MB each)
  unsigned short* WkT = (unsigned short*)(ws + 26*MB);
  unsigned short* WvT = (unsigned short*)(ws + 28*MB);
  unsigned short* WoT = (unsigned short*)(ws + 30*MB);
  unsigned short* Qp  = (unsigned short*)(ws + 32*MB);  // projected Q (scaled*log2e), natural layout
  unsigned short* Kp  = (unsigned short*)(ws + 40*MB);  // projected K, natural layout
  unsigned short* VTb = (unsigned short*)(ws + 48*MB);  // projected V, [b][h][d][s]
  unsigned short* ctx = (unsigned short*)(ws + 56*MB);  // attention output, natural layout
  // overlays on qb/kb/vb -- all free after qkv_gemm:
  unsigned short* Op  = (unsigned short*)(ws + 0*MB);   // 2 x 8MB raw partial O (bf16)
  float*          mlp = (float*)(ws + 16*MB);           // 2 x 0.5MB (m,l) per (split,row)
  float*          gw  = (float*)(ws + 17*MB);           // 16KB mask-folded gauss table

  cast_qkv<<<dim3((BS*SEQ*DIM)/(256*8), 3), 256, 0, stream>>>(query, key, value, qb, kb, vb);
  wcast_t<<<dim3(DIM/32, DIM/32, 4), 256, 0, stream>>>(Wq, Wk, Wv, Wo, WqT, WkT, WvT, WoT);
  qkv_gemm<<<dim3(NWG, 3), 256, 0, stream>>>(qb, kb, vb, WqT, WkT, WvT, bq, bk, bv, Qp, Kp, VTb);
  gw_prep<<<(BS*SEQ)/256, 256, 0, stream>>>(gauss, mask, gw);   // after qkv_gemm: reuses vb space
  attn_part<<<BS*NH*(SEQ/64)*2, 256, 0, stream>>>(Qp, Kp, VTb, gw, Op, mlp);
  attn_reduce<<<(NROWS*8)/256, 256, 0, stream>>>(Op, mlp, ctx);
  out_gemm<<<NWG, 256, 0, stream>>>(ctx, WoT, bo, (float*)d_out);
}

// Round 13
// 153.445 us; speedup vs baseline: 1.6794x; 1.6794x over previous
//
#include <hip/hip_runtime.h>
#include <stdint.h>

#define BS 4
#define SEQ 1024
#define DIM 1024
#define NH 16
#define DH 64
#define MROWS (BS*SEQ)   // 4096

#define MT 128
#define NT 128
#define KT 32
#define NBM (MROWS/MT)   // 32
#define NBN (DIM/NT)     // 8
#define NWG (NBM*NBN)    // 256
#define NKT (DIM/KT)     // 32

typedef __attribute__((ext_vector_type(8))) short bf16x8;
typedef __attribute__((ext_vector_type(4))) float f32x4;
typedef __attribute__((ext_vector_type(8))) unsigned short ushort8;
typedef __attribute__((ext_vector_type(4))) float float4v;
typedef __attribute__((ext_vector_type(4))) int int4v;
typedef __attribute__((ext_vector_type(2))) unsigned int uint32x2;

__device__ __forceinline__ unsigned short f2bf(float x) {
  union { float f; uint32_t u; } a; a.f = x;
  uint32_t r = (a.u + 0x7FFFu + ((a.u >> 16) & 1u)) >> 16;  // RNE
  return (unsigned short)r;
}

// packed f32x2 -> bf16x2 (lo = first arg); no builtin on gfx950 -> inline asm (T12)
__device__ __forceinline__ uint32_t cvtpk_bf16(float lo, float hi) {
  uint32_t d;
  asm("v_cvt_pk_bf16_f32 %0, %1, %2" : "=v"(d) : "v"(lo), "v"(hi));
  return d;
}

// raw 2^x (softmax runs in log2 domain; log2e folded into Q scale upstream)
__device__ __forceinline__ float exp2a(float x) {
  float r;
  asm("v_exp_f32 %0, %1" : "=v"(r) : "v"(x));
  return r;
}

typedef const void __attribute__((address_space(1)))* gvp;
typedef void __attribute__((address_space(3)))* lvp;
__device__ __forceinline__ void gld_lds16(const void* g, void* l) {
  // async global->LDS, 16B/lane; LDS dest = wave-uniform base + lane*16
  __builtin_amdgcn_global_load_lds((gvp)g, (lvp)l, 16, 0, 0);
}

// ---------------- fp32 -> bf16 cast (query/key/value) ----------------
__global__ __launch_bounds__(256) void cast_qkv(
    const float* __restrict__ q, const float* __restrict__ k, const float* __restrict__ v,
    unsigned short* __restrict__ qo, unsigned short* __restrict__ ko, unsigned short* __restrict__ vo) {
  const float* s = blockIdx.y == 0 ? q : (blockIdx.y == 1 ? k : v);
  unsigned short* d = blockIdx.y == 0 ? qo : (blockIdx.y == 1 ? ko : vo);
  size_t i = ((size_t)blockIdx.x * 256 + threadIdx.x) * 8;
  float4v x0 = *(const float4v*)(s + i);
  float4v x1 = *(const float4v*)(s + i + 4);
  ushort8 r;
  r[0]=f2bf(x0[0]); r[1]=f2bf(x0[1]); r[2]=f2bf(x0[2]); r[3]=f2bf(x0[3]);
  r[4]=f2bf(x1[0]); r[5]=f2bf(x1[1]); r[6]=f2bf(x1[2]); r[7]=f2bf(x1[3]);
  *(ushort8*)(d + i) = r;
}

// ---------------- mask-folded gauss table: gw[b][s] = mask ? gauss+1e-10 : 0 ----------------
__global__ __launch_bounds__(256) void gw_prep(
    const float* __restrict__ gauss, const int* __restrict__ mask, float* __restrict__ gw) {
  int i = blockIdx.x * 256 + threadIdx.x;
  gw[i] = mask[i] ? gauss[i] + 1e-10f : 0.f;
}

// ---------------- weight cast + transpose: WT[n][k] = bf16(W[k][n]) ----------------
__global__ __launch_bounds__(256) void wcast_t(
    const float* __restrict__ w0, const float* __restrict__ w1,
    const float* __restrict__ w2, const float* __restrict__ w3,
    unsigned short* __restrict__ t0, unsigned short* __restrict__ t1,
    unsigned short* __restrict__ t2, unsigned short* __restrict__ t3) {
  __shared__ float tile[32][33];
  const float* W = blockIdx.z == 0 ? w0 : blockIdx.z == 1 ? w1 : blockIdx.z == 2 ? w2 : w3;
  unsigned short* T = blockIdx.z == 0 ? t0 : blockIdx.z == 1 ? t1 : blockIdx.z == 2 ? t2 : t3;
  int tx = threadIdx.x & 31, ty = threadIdx.x >> 5;   // 32 x 8
  int bx = blockIdx.x, by = blockIdx.y;
#pragma unroll
  for (int j = 0; j < 4; j++)
    tile[ty + 8*j][tx] = W[(size_t)(by*32 + ty + 8*j)*DIM + bx*32 + tx];
  __syncthreads();
#pragma unroll
  for (int j = 0; j < 4; j++)
    T[(size_t)(bx*32 + ty + 8*j)*DIM + by*32 + tx] = f2bf(tile[tx][ty + 8*j]);
}

// ---------------- GEMM core: m97-exact 128x128 tile ----------------
// 4 waves (2x2), each computes a 64x64 sub-tile: acc[4][4], 16 MFMA/K-step.
// MODE 0: bf16 out, (acc+bias)*scale; MODE 2: bf16, per-head transposed
// VT[b][h][d][s]; MODE 3: f32 out.
template<int MODE>
__device__ __forceinline__ void gemm_core(
    unsigned short* lds,
    const unsigned short* __restrict__ A, const unsigned short* __restrict__ BT,
    const float* __restrict__ bias, void* __restrict__ outp, float scale) {
  unsigned short* Abase = lds;                 // 2 x MT*KT
  unsigned short* Bbase = lds + 2*MT*KT;       // 2 x NT*KT
  int id = blockIdx.x;
  int sw = (id & 7) * (NWG/8) + (id >> 3);     // XCD swizzle (bijective, 256%8==0)
  int bn = sw & (NBN-1), bm = sw >> 3;         // bn-fast: XCD holds 1MB A-panel + 2MB B (<L2)
  int tid = threadIdx.x, w = tid >> 6, l = tid & 63;
  int wr = w >> 1, wc = w & 1;
  int lr = l & 15, lg = l >> 4;

  auto stage = [&](int buf, int kt) {
    const unsigned short* a0 = A + (size_t)(bm*MT + w*32 + (l>>2))*DIM + kt*KT + (l&3)*8;
    gld_lds16(a0,          Abase + buf*MT*KT + (w*32)*KT);
    gld_lds16(a0 + 16*DIM, Abase + buf*MT*KT + (w*32 + 16)*KT);
    const unsigned short* b0 = BT + (size_t)(bn*NT + w*32 + (l>>2))*DIM + kt*KT + (l&3)*8;
    gld_lds16(b0,          Bbase + buf*NT*KT + (w*32)*KT);
    gld_lds16(b0 + 16*DIM, Bbase + buf*NT*KT + (w*32 + 16)*KT);
  };

  f32x4 acc[4][4] = {};
  int buf = 0;
  stage(0, 0);
  __syncthreads();
  for (int kt = 0; kt < NKT; kt++) {
    if (kt + 1 < NKT) stage(buf ^ 1, kt + 1);
    unsigned short* As = Abase + buf*MT*KT;
    unsigned short* Bs = Bbase + buf*NT*KT;
    bf16x8 af[4], bf_[4];
#pragma unroll
    for (int mi = 0; mi < 4; mi++)
      af[mi] = *(const bf16x8*)&As[(wr*64 + mi*16 + lr)*KT + lg*8];
#pragma unroll
    for (int ni = 0; ni < 4; ni++)
      bf_[ni] = *(const bf16x8*)&Bs[(wc*64 + ni*16 + lr)*KT + lg*8];
#pragma unroll
    for (int mi = 0; mi < 4; mi++)
#pragma unroll
      for (int ni = 0; ni < 4; ni++)
        acc[mi][ni] = __builtin_amdgcn_mfma_f32_16x16x32_bf16(af[mi], bf_[ni], acc[mi][ni], 0, 0, 0);
    __syncthreads();   // drains vmcnt for the staged next tile + protects buffer reuse
    buf ^= 1;
  }

  int row0 = bm*MT + wr*64;
  int col0 = bn*NT + wc*64;
#pragma unroll
  for (int ni = 0; ni < 4; ni++) {
    int col = col0 + ni*16 + lr;
    float bv = bias[col];
#pragma unroll
    for (int mi = 0; mi < 4; mi++)
#pragma unroll
      for (int r = 0; r < 4; r++) {
        int row = row0 + mi*16 + lg*4 + r;
        float val = acc[mi][ni][r] + bv;
        if (MODE == 0) {
          ((unsigned short*)outp)[(size_t)row*DIM + col] = f2bf(val * scale);
        } else if (MODE == 2) {
          int b = row >> 10, s = row & 1023, h = col >> 6, d = col & 63;
          ((unsigned short*)outp)[(size_t)((b*NH + h)*DH + d)*SEQ + s] = f2bf(val);
        } else {
          ((float*)outp)[(size_t)row*DIM + col] = val;
        }
      }
  }
}

__global__ __launch_bounds__(256) void qkv_gemm(
    const unsigned short* __restrict__ qb, const unsigned short* __restrict__ kb,
    const unsigned short* __restrict__ vb,
    const unsigned short* __restrict__ WqT, const unsigned short* __restrict__ WkT,
    const unsigned short* __restrict__ WvT,
    const float* __restrict__ bq, const float* __restrict__ bk, const float* __restrict__ bv,
    unsigned short* __restrict__ Qp, unsigned short* __restrict__ Kp,
    unsigned short* __restrict__ VT) {
  __shared__ __align__(16) unsigned short lds[2*(MT+NT)*KT];
  int z = blockIdx.y;
  // Q scale = 1/sqrt(64) * log2(e): softmax runs in exp2 domain downstream
  if (z == 0)      gemm_core<0>(lds, qb, WqT, bq, Qp, 0.18033688011112042f);
  else if (z == 1) gemm_core<0>(lds, kb, WkT, bk, Kp, 1.0f);
  else             gemm_core<2>(lds, vb, WvT, bv, VT, 1.0f);
}

__global__ __launch_bounds__(256) void out_gemm(
    const unsigned short* __restrict__ ctx, const unsigned short* __restrict__ WoT,
    const float* __restrict__ bo, float* __restrict__ out) {
  __shared__ __align__(16) unsigned short lds[2*(MT+NT)*KT];
  gemm_core<3>(lds, ctx, WoT, bo, out, 1.0f);
}

// ---------------- flash attention (R10 champion + chain-shortening edits) ----------------
// grid 1024, head-major (bh = blk&63): K+V L2-resident per XCD. 4 waves x 16 q-rows,
// KVBLK=64 (16 iters). K: async global_load_lds double-buffer (zero-VGPR prefetch,
// the only scheme that beats hipcc's default - R4/5/7/8/9), XOR-swizzled.
// V + gw: plain compiler-scheduled loads (gw table 16KB, L2-hot, read direct -
// gwl LDS copy dropped -> LDS 25600B -> 6 blocks/CU).
// Chain edits vs R10: (1) NO manual lgkmcnt/sched_barrier fence before P re-read -
// compiler emits fine-grained lgkmcnt (validated by R12's attn_part) and can now
// interleave V/gw loads across the P round-trip; (2) l_ cross-lane sum DEFERRED
// to epilogue (per-lane partial, rescaled by alpha like the full sum): removes
// 2 shfl x 16 iters (~1100 serial cyc/wave). Swapped QK^T, exp2 domain, T13
// defer-max. NO launch_bounds occupancy forcing (R12 lesson: spill disaster).
__global__ __launch_bounds__(256, 4) void attn(
    const unsigned short* __restrict__ Qp, const unsigned short* __restrict__ Kp,
    const unsigned short* __restrict__ VT, const float* __restrict__ gw,
    unsigned short* __restrict__ ctx) {
  __shared__ __align__(16) unsigned short Klds[2*64*64];  // 16KB double-buffered K tile
  __shared__ __align__(16) unsigned short P[4][16][72];   // 9216B per-wave slab, padded
  int blk = blockIdx.x;
  int bh = blk & 63, qt = blk >> 6;        // head-major: head bh pinned to XCD bh%8
  int b = bh >> 4, h = bh & 15;
  int tid = threadIdx.x, w = tid >> 6, l = tid & 63;
  int lr = l & 15, lg = l >> 4;
  int q0 = qt*64 + w*16;

  const unsigned short* Qb = Qp + (size_t)(b*SEQ + q0 + lr)*DIM + h*DH + lg*8;
  bf16x8 aq0 = *(const bf16x8*)Qb;
  bf16x8 aq1 = *(const bf16x8*)(Qb + 32);

  float m_ = -1e30f, l_ = 0.f;             // m_ shared per row; l_ = PER-LANE partial sum
  f32x4 cacc[4] = {};                      // O^T[d = dt*16+lg*4+r][q = lr]

  const unsigned short* Krow0 = Kp + (size_t)(b*SEQ)*DIM + h*DH;
  const unsigned short* Vb0   = VT + (size_t)((b*NH + h)*DH + lr)*SEQ + lg*8;
  const float* gwb = gw + b*SEQ;

  // staging geometry: lane l covers row (l>>3), 16B slot (l&7); source pre-swizzled by row&7
  int srow = l >> 3;
  int scol = ((l & 7) ^ srow) * 8;
  auto stageK = [&](int buf, int key0) {
    gld_lds16(Krow0 + (size_t)(key0 + w*16 +     srow)*DIM + scol, Klds + buf*64*64 + (w*16    )*64);
    gld_lds16(Krow0 + (size_t)(key0 + w*16 + 8 + srow)*DIM + scol, Klds + buf*64*64 + (w*16 + 8)*64);
  };

  stageK(0, 0);
  __syncthreads();   // K[0] ready
  int buf = 0;
  for (int kt = 0; kt < 16; kt++) {
    int key0 = kt*64;
    // ---- issue next-K stage (async DMA, zero VGPR; drained by end-of-iter barrier) ----
    if (kt < 15) stageK(buf ^ 1, key0 + 64);
    // ---- S^T = mfma(K, Q) from LDS (swizzled read): sa[nf][r] = S[key][q=lr] ----
    const unsigned short* Kt = Klds + buf*64*64;
    f32x4 sa[4] = {};
#pragma unroll
    for (int nf = 0; nf < 4; nf++) {
      int r1 = nf*16 + lr;
      int rx = r1 & 7;
      bf16x8 k0 = *(const bf16x8*)&Kt[r1*64 + ((lg       ^ rx) * 8)];
      bf16x8 k1 = *(const bf16x8*)&Kt[r1*64 + (((lg + 4) ^ rx) * 8)];
      sa[nf] = __builtin_amdgcn_mfma_f32_16x16x32_bf16(k0, aq0, sa[nf], 0, 0, 0);
      sa[nf] = __builtin_amdgcn_mfma_f32_16x16x32_bf16(k1, aq1, sa[nf], 0, 0, 0);
    }
    // ---- V loads (plain, compiler-scheduled) ----
    bf16x8 vf[4][2];
#pragma unroll
    for (int dt = 0; dt < 4; dt++) {
      vf[dt][0] = *(const bf16x8*)(Vb0 + (size_t)(dt*16)*SEQ + key0);
      vf[dt][1] = *(const bf16x8*)(Vb0 + (size_t)(dt*16)*SEQ + key0 + 32);
    }
    // ---- online softmax in exp2 domain; tree max (2 shfl); T13 defer-max ----
    float t0 = fmaxf(fmaxf(sa[0][0], sa[0][1]), fmaxf(sa[0][2], sa[0][3]));
    float t1 = fmaxf(fmaxf(sa[1][0], sa[1][1]), fmaxf(sa[1][2], sa[1][3]));
    float t2 = fmaxf(fmaxf(sa[2][0], sa[2][1]), fmaxf(sa[2][2], sa[2][3]));
    float t3 = fmaxf(fmaxf(sa[3][0], sa[3][1]), fmaxf(sa[3][2], sa[3][3]));
    float mx = fmaxf(fmaxf(t0, t1), fmaxf(t2, t3));
    mx = fmaxf(mx, __shfl_xor(mx, 16));
    mx = fmaxf(mx, __shfl_xor(mx, 32));
    if (!__all(mx - m_ <= 8.0f)) {         // rescale only on real max growth
      float mn = fmaxf(m_, mx);
      float alpha = exp2a(m_ - mn);
      m_ = mn;
      l_ *= alpha;                         // per-lane partial scales identically
#pragma unroll
      for (int dt = 0; dt < 4; dt++)
#pragma unroll
        for (int r = 0; r < 4; r++) cacc[dt][r] *= alpha;
    }
    uint32_t u[4][2];
#pragma unroll
    for (int nf = 0; nf < 4; nf++) {
      float4v g = *(const float4v*)&gwb[key0 + nf*16 + lg*4];   // L2-hot table
      float p0 = exp2a(sa[nf][0] - m_) * g[0];
      float p1 = exp2a(sa[nf][1] - m_) * g[1];
      float p2 = exp2a(sa[nf][2] - m_) * g[2];
      float p3 = exp2a(sa[nf][3] - m_) * g[3];
      l_ += (p0 + p1) + (p2 + p3);         // per-lane partial; cross-lane deferred
      u[nf][0] = cvtpk_bf16(p0, p1);
      u[nf][1] = cvtpk_bf16(p2, p3);
    }
    // ---- P[q=lr][key]: 4x ds_write_b64; NO manual fence (compiler orders re-read) ----
#pragma unroll
    for (int nf = 0; nf < 4; nf++) {
      uint32x2 uu; uu[0] = u[nf][0]; uu[1] = u[nf][1];
      *(uint32x2*)&P[w][lr][nf*16 + lg*4] = uu;
    }
    bf16x8 ap0 = *(const bf16x8*)&P[w][lr][lg*8];        // B-frag: keys 0..31
    bf16x8 ap1 = *(const bf16x8*)&P[w][lr][32 + lg*8];   // B-frag: keys 32..63
    // ---- O^T += mfma(V^T, P) ----
#pragma unroll
    for (int dt = 0; dt < 4; dt++) {
      cacc[dt] = __builtin_amdgcn_mfma_f32_16x16x32_bf16(vf[dt][0], ap0, cacc[dt], 0, 0, 0);
      cacc[dt] = __builtin_amdgcn_mfma_f32_16x16x32_bf16(vf[dt][1], ap1, cacc[dt], 0, 0, 0);
    }
    __syncthreads();   // K dbuf swap: waves done reading K[t]; next-K stage drains here
    buf ^= 1;
  }

  // ---- epilogue: one cross-lane sum reduce, normalize, pack, 4x b64 stores ----
  float rs = l_;
  rs += __shfl_xor(rs, 16);
  rs += __shfl_xor(rs, 32);
  float inv = 1.0f / rs;
  size_t row = (size_t)(b*SEQ + q0 + lr)*DIM + h*DH;
#pragma unroll
  for (int dt = 0; dt < 4; dt++) {
    uint32x2 e;
    e[0] = cvtpk_bf16(cacc[dt][0]*inv, cacc[dt][1]*inv);
    e[1] = cvtpk_bf16(cacc[dt][2]*inv, cacc[dt][3]*inv);
    *(uint32x2*)&ctx[row + dt*16 + lg*4] = e;
  }
}

// ---------------- launch ----------------
extern "C" void kernel_launch(void* const* d_in, const int* in_sizes, int n_in,
                              void* d_out, int out_size, void* d_ws, size_t ws_size,
                              hipStream_t stream) {
  const float* query = (const float*)d_in[0];
  const float* key   = (const float*)d_in[1];
  const float* value = (const float*)d_in[2];
  const int*   mask  = (const int*)d_in[3];
  const float* gauss = (const float*)d_in[4];
  const float* Wq = (const float*)d_in[5];
  const float* bq = (const float*)d_in[6];
  const float* Wk = (const float*)d_in[7];
  const float* bk = (const float*)d_in[8];
  const float* Wv = (const float*)d_in[9];
  const float* bv = (const float*)d_in[10];
  const float* Wo = (const float*)d_in[11];
  const float* bo = (const float*)d_in[12];

  char* ws = (char*)d_ws;
  const size_t MB = 1024*1024;
  unsigned short* qb  = (unsigned short*)(ws + 0*MB);   // bf16 casts of inputs (8MB each)
  unsigned short* kb  = (unsigned short*)(ws + 8*MB);
  unsigned short* vb  = (unsigned short*)(ws + 16*MB);
  unsigned short* WqT = (unsigned short*)(ws + 24*MB);  // transposed bf16 weights (2MB each)
  unsigned short* WkT = (unsigned short*)(ws + 26*MB);
  unsigned short* WvT = (unsigned short*)(ws + 28*MB);
  unsigned short* WoT = (unsigned short*)(ws + 30*MB);
  unsigned short* Qp  = (unsigned short*)(ws + 32*MB);  // projected Q (scaled*log2e), natural layout
  unsigned short* Kp  = (unsigned short*)(ws + 40*MB);  // projected K, natural layout
  unsigned short* VTb = (unsigned short*)(ws + 48*MB);  // projected V, [b][h][d][s]
  unsigned short* ctx = (unsigned short*)(ws + 56*MB);  // attention output, natural layout
  float*          gw  = (float*)(ws + 0*MB);            // 16KB mask-folded gauss table
                                                        // (overlays qb AFTER qkv_gemm consumed it)

  cast_qkv<<<dim3((BS*SEQ*DIM)/(256*8), 3), 256, 0, stream>>>(query, key, value, qb, kb, vb);
  wcast_t<<<dim3(DIM/32, DIM/32, 4), 256, 0, stream>>>(Wq, Wk, Wv, Wo, WqT, WkT, WvT, WoT);
  qkv_gemm<<<dim3(NWG, 3), 256, 0, stream>>>(qb, kb, vb, WqT, WkT, WvT, bq, bk, bv, Qp, Kp, VTb);
  gw_prep<<<(BS*SEQ)/256, 256, 0, stream>>>(gauss, mask, gw);   // after qkv_gemm: reuses qb space
  attn<<<BS*NH*(SEQ/64), 256, 0, stream>>>(Qp, Kp, VTb, gw, ctx);
  out_gemm<<<NWG, 256, 0, stream>>>(ctx, WoT, bo, (float*)d_out);
}

// Round 14
// 126.995 us; speedup vs baseline: 2.0292x; 1.2083x over previous
//
#include <hip/hip_runtime.h>
#include <stdint.h>

#define BS 4
#define SEQ 1024
#define DIM 1024
#define NH 16
#define DH 64
#define MROWS (BS*SEQ)   // 4096

#define MT 128
#define NT 128
#define KT 32
#define NBM (MROWS/MT)   // 32
#define NBN (DIM/NT)     // 8
#define NWG (NBM*NBN)    // 256
#define NKT (DIM/KT)     // 32

typedef __attribute__((ext_vector_type(8))) short bf16x8;
typedef __attribute__((ext_vector_type(4))) float f32x4;
typedef __attribute__((ext_vector_type(8))) unsigned short ushort8;
typedef __attribute__((ext_vector_type(4))) float float4v;
typedef __attribute__((ext_vector_type(4))) int int4v;
typedef __attribute__((ext_vector_type(2))) unsigned int uint32x2;

__device__ __forceinline__ unsigned short f2bf(float x) {
  union { float f; uint32_t u; } a; a.f = x;
  uint32_t r = (a.u + 0x7FFFu + ((a.u >> 16) & 1u)) >> 16;  // RNE
  return (unsigned short)r;
}

// packed f32x2 -> bf16x2 (lo = first arg); no builtin on gfx950 -> inline asm (T12)
__device__ __forceinline__ uint32_t cvtpk_bf16(float lo, float hi) {
  uint32_t d;
  asm("v_cvt_pk_bf16_f32 %0, %1, %2" : "=v"(d) : "v"(lo), "v"(hi));
  return d;
}

// raw 2^x (softmax runs in log2 domain; log2e folded into Q scale upstream)
__device__ __forceinline__ float exp2a(float x) {
  float r;
  asm("v_exp_f32 %0, %1" : "=v"(r) : "v"(x));
  return r;
}

typedef const void __attribute__((address_space(1)))* gvp;
typedef void __attribute__((address_space(3)))* lvp;
__device__ __forceinline__ void gld_lds16(const void* g, void* l) {
  // async global->LDS, 16B/lane; LDS dest = wave-uniform base + lane*16
  __builtin_amdgcn_global_load_lds((gvp)g, (lvp)l, 16, 0, 0);
}

// ---------------- fp32 -> bf16 cast (query/key/value) ----------------
__global__ __launch_bounds__(256) void cast_qkv(
    const float* __restrict__ q, const float* __restrict__ k, const float* __restrict__ v,
    unsigned short* __restrict__ qo, unsigned short* __restrict__ ko, unsigned short* __restrict__ vo) {
  const float* s = blockIdx.y == 0 ? q : (blockIdx.y == 1 ? k : v);
  unsigned short* d = blockIdx.y == 0 ? qo : (blockIdx.y == 1 ? ko : vo);
  size_t i = ((size_t)blockIdx.x * 256 + threadIdx.x) * 8;
  float4v x0 = *(const float4v*)(s + i);
  float4v x1 = *(const float4v*)(s + i + 4);
  ushort8 r;
  r[0]=f2bf(x0[0]); r[1]=f2bf(x0[1]); r[2]=f2bf(x0[2]); r[3]=f2bf(x0[3]);
  r[4]=f2bf(x1[0]); r[5]=f2bf(x1[1]); r[6]=f2bf(x1[2]); r[7]=f2bf(x1[3]);
  *(ushort8*)(d + i) = r;
}

// ---------------- weight cast + transpose: WT[n][k] = bf16(W[k][n]) ----------------
__global__ __launch_bounds__(256) void wcast_t(
    const float* __restrict__ w0, const float* __restrict__ w1,
    const float* __restrict__ w2, const float* __restrict__ w3,
    unsigned short* __restrict__ t0, unsigned short* __restrict__ t1,
    unsigned short* __restrict__ t2, unsigned short* __restrict__ t3) {
  __shared__ float tile[32][33];
  const float* W = blockIdx.z == 0 ? w0 : blockIdx.z == 1 ? w1 : blockIdx.z == 2 ? w2 : w3;
  unsigned short* T = blockIdx.z == 0 ? t0 : blockIdx.z == 1 ? t1 : blockIdx.z == 2 ? t2 : t3;
  int tx = threadIdx.x & 31, ty = threadIdx.x >> 5;   // 32 x 8
  int bx = blockIdx.x, by = blockIdx.y;
#pragma unroll
  for (int j = 0; j < 4; j++)
    tile[ty + 8*j][tx] = W[(size_t)(by*32 + ty + 8*j)*DIM + bx*32 + tx];
  __syncthreads();
#pragma unroll
  for (int j = 0; j < 4; j++)
    T[(size_t)(bx*32 + ty + 8*j)*DIM + by*32 + tx] = f2bf(tile[tx][ty + 8*j]);
}

// ---------------- GEMM core: m97-exact 128x128 tile ----------------
// 4 waves (2x2), each computes a 64x64 sub-tile: acc[4][4], 16 MFMA/K-step.
// MODE 0: bf16 out, (acc+bias)*scale; MODE 2: bf16, per-head transposed
// VT[b][h][d][s]; MODE 3: f32 out.
template<int MODE>
__device__ __forceinline__ void gemm_core(
    unsigned short* lds,
    const unsigned short* __restrict__ A, const unsigned short* __restrict__ BT,
    const float* __restrict__ bias, void* __restrict__ outp, float scale) {
  unsigned short* Abase = lds;                 // 2 x MT*KT
  unsigned short* Bbase = lds + 2*MT*KT;       // 2 x NT*KT
  int id = blockIdx.x;
  int sw = (id & 7) * (NWG/8) + (id >> 3);     // XCD swizzle (bijective, 256%8==0)
  int bn = sw & (NBN-1), bm = sw >> 3;         // bn-fast: XCD holds 1MB A-panel + 2MB B (<L2)
  int tid = threadIdx.x, w = tid >> 6, l = tid & 63;
  int wr = w >> 1, wc = w & 1;
  int lr = l & 15, lg = l >> 4;

  auto stage = [&](int buf, int kt) {
    const unsigned short* a0 = A + (size_t)(bm*MT + w*32 + (l>>2))*DIM + kt*KT + (l&3)*8;
    gld_lds16(a0,          Abase + buf*MT*KT + (w*32)*KT);
    gld_lds16(a0 + 16*DIM, Abase + buf*MT*KT + (w*32 + 16)*KT);
    const unsigned short* b0 = BT + (size_t)(bn*NT + w*32 + (l>>2))*DIM + kt*KT + (l&3)*8;
    gld_lds16(b0,          Bbase + buf*NT*KT + (w*32)*KT);
    gld_lds16(b0 + 16*DIM, Bbase + buf*NT*KT + (w*32 + 16)*KT);
  };

  f32x4 acc[4][4] = {};
  int buf = 0;
  stage(0, 0);
  __syncthreads();
  for (int kt = 0; kt < NKT; kt++) {
    if (kt + 1 < NKT) stage(buf ^ 1, kt + 1);
    unsigned short* As = Abase + buf*MT*KT;
    unsigned short* Bs = Bbase + buf*NT*KT;
    bf16x8 af[4], bf_[4];
#pragma unroll
    for (int mi = 0; mi < 4; mi++)
      af[mi] = *(const bf16x8*)&As[(wr*64 + mi*16 + lr)*KT + lg*8];
#pragma unroll
    for (int ni = 0; ni < 4; ni++)
      bf_[ni] = *(const bf16x8*)&Bs[(wc*64 + ni*16 + lr)*KT + lg*8];
#pragma unroll
    for (int mi = 0; mi < 4; mi++)
#pragma unroll
      for (int ni = 0; ni < 4; ni++)
        acc[mi][ni] = __builtin_amdgcn_mfma_f32_16x16x32_bf16(af[mi], bf_[ni], acc[mi][ni], 0, 0, 0);
    __syncthreads();   // drains vmcnt for the staged next tile + protects buffer reuse
    buf ^= 1;
  }

  int row0 = bm*MT + wr*64;
  int col0 = bn*NT + wc*64;
#pragma unroll
  for (int ni = 0; ni < 4; ni++) {
    int col = col0 + ni*16 + lr;
    float bv = bias[col];
#pragma unroll
    for (int mi = 0; mi < 4; mi++)
#pragma unroll
      for (int r = 0; r < 4; r++) {
        int row = row0 + mi*16 + lg*4 + r;
        float val = acc[mi][ni][r] + bv;
        if (MODE == 0) {
          ((unsigned short*)outp)[(size_t)row*DIM + col] = f2bf(val * scale);
        } else if (MODE == 2) {
          int b = row >> 10, s = row & 1023, h = col >> 6, d = col & 63;
          ((unsigned short*)outp)[(size_t)((b*NH + h)*DH + d)*SEQ + s] = f2bf(val);
        } else {
          ((float*)outp)[(size_t)row*DIM + col] = val;
        }
      }
  }
}

__global__ __launch_bounds__(256) void qkv_gemm(
    const unsigned short* __restrict__ qb, const unsigned short* __restrict__ kb,
    const unsigned short* __restrict__ vb,
    const unsigned short* __restrict__ WqT, const unsigned short* __restrict__ WkT,
    const unsigned short* __restrict__ WvT,
    const float* __restrict__ bq, const float* __restrict__ bk, const float* __restrict__ bv,
    unsigned short* __restrict__ Qp, unsigned short* __restrict__ Kp,
    unsigned short* __restrict__ VT) {
  __shared__ __align__(16) unsigned short lds[2*(MT+NT)*KT];
  int z = blockIdx.y;
  // Q scale = 1/sqrt(64) * log2(e): softmax runs in exp2 domain downstream
  if (z == 0)      gemm_core<0>(lds, qb, WqT, bq, Qp, 0.18033688011112042f);
  else if (z == 1) gemm_core<0>(lds, kb, WkT, bk, Kp, 1.0f);
  else             gemm_core<2>(lds, vb, WvT, bv, VT, 1.0f);
}

__global__ __launch_bounds__(256) void out_gemm(
    const unsigned short* __restrict__ ctx, const unsigned short* __restrict__ WoT,
    const float* __restrict__ bo, float* __restrict__ out) {
  __shared__ __align__(16) unsigned short lds[2*(MT+NT)*KT];
  gemm_core<3>(lds, ctx, WoT, bo, out, 1.0f);
}

// ---------------- flash attention (R10 champion + V through LDS dbuf) ----------------
// grid 1024, head-major (bh = blk&63): K+V L2-resident per XCD. 4 waves x 16 q-rows,
// KVBLK=64 (16 iters). R10-exact schedule (gwl stash, manual P fence, per-iter l_
// reduce, exp2 domain, T13 defer-max) with ONE delta: V is staged through a
// second zero-VGPR global_load_lds double-buffer, like K. Rationale: all 4 waves
// read the IDENTICAL V tile (address independent of w) -> staging removes 4x
// redundant L2 reads AND the 220-400cyc exposed V latency (compiler provably
// sinks plain V loads to PV: VGPR=56 across R6/R10/R13). V[t+1] staged at iter
// top, drained by the existing end-of-iter barrier - no new sync. LDS 45.3KB ->
// 3 blocks/CU (measured occupancy was already ~3.2 effective).
__global__ __launch_bounds__(256, 4) void attn(
    const unsigned short* __restrict__ Qp, const unsigned short* __restrict__ Kp,
    const unsigned short* __restrict__ VT, const int* __restrict__ mask,
    const float* __restrict__ gauss, unsigned short* __restrict__ ctx) {
  __shared__ __align__(16) unsigned short Klds[2*64*64];  // 16KB double-buffered K tile
  __shared__ __align__(16) unsigned short Vlds[2*64*64];  // 16KB double-buffered V tile
  __shared__ __align__(16) unsigned short P[4][16][72];   // 9216B per-wave slab, padded
  __shared__ float gwl[SEQ];                              // mask-folded gauss weights
  int blk = blockIdx.x;
  int bh = blk & 63, qt = blk >> 6;        // head-major: head bh pinned to XCD bh%8
  int b = bh >> 4, h = bh & 15;
  int tid = threadIdx.x, w = tid >> 6, l = tid & 63;
  int lr = l & 15, lg = l >> 4;
  int q0 = qt*64 + w*16;

  // ---- stash mask-folded gauss row in LDS (once; covered by prologue barrier) ----
  {
    int i4 = tid * 4;
    float4v g4 = *(const float4v*)(gauss + b*SEQ + i4);
    int4v   m4 = *(const int4v*)(mask + b*SEQ + i4);
#pragma unroll
    for (int j = 0; j < 4; j++) gwl[i4 + j] = m4[j] ? g4[j] + 1e-10f : 0.f;
  }

  const unsigned short* Qb = Qp + (size_t)(b*SEQ + q0 + lr)*DIM + h*DH + lg*8;
  bf16x8 aq0 = *(const bf16x8*)Qb;
  bf16x8 aq1 = *(const bf16x8*)(Qb + 32);

  float m_ = -1e30f, l_ = 0.f;             // per-lane scalars (q = lr), log2 domain
  f32x4 cacc[4] = {};                      // O^T[d = dt*16+lg*4+r][q = lr]

  const unsigned short* Krow0 = Kp + (size_t)(b*SEQ)*DIM + h*DH;   // key-rows, stride DIM
  const unsigned short* Vrow0 = VT + (size_t)((b*NH + h)*DH)*SEQ;  // d-rows, stride SEQ

  // staging geometry (shared by K and V): per instr, lane l covers row (l>>3),
  // 16B slot (l&7); source slot pre-swizzled by row&7 (both-sides swizzle rule)
  int srow = l >> 3;
  int scol = ((l & 7) ^ srow) * 8;
  auto stageK = [&](int buf, int key0) {
    gld_lds16(Krow0 + (size_t)(key0 + w*16 +     srow)*DIM + scol, Klds + buf*64*64 + (w*16    )*64);
    gld_lds16(Krow0 + (size_t)(key0 + w*16 + 8 + srow)*DIM + scol, Klds + buf*64*64 + (w*16 + 8)*64);
  };
  auto stageV = [&](int buf, int key0) {
    gld_lds16(Vrow0 + (size_t)(w*16 +     srow)*SEQ + key0 + scol, Vlds + buf*64*64 + (w*16    )*64);
    gld_lds16(Vrow0 + (size_t)(w*16 + 8 + srow)*SEQ + key0 + scol, Vlds + buf*64*64 + (w*16 + 8)*64);
  };

  stageK(0, 0);
  stageV(0, 0);
  __syncthreads();   // gwl + K[0] + V[0] ready
  int buf = 0;
  int rx = lr & 7;   // swizzle index: (row&7) for all rows read below (rows = lr mod 16)
  for (int kt = 0; kt < 16; kt++) {
    int key0 = kt*64;
    // ---- issue next K+V stages (async DMA, zero VGPR; drained by end-of-iter barrier) ----
    if (kt < 15) { stageK(buf ^ 1, key0 + 64); stageV(buf ^ 1, key0 + 64); }
    // ---- S^T = mfma(K, Q) from LDS (swizzled read): sa[nf][r] = S[key][q=lr] ----
    const unsigned short* Kt = Klds + buf*64*64;
    f32x4 sa[4] = {};
#pragma unroll
    for (int nf = 0; nf < 4; nf++) {
      int r1 = nf*16 + lr;
      bf16x8 k0 = *(const bf16x8*)&Kt[r1*64 + ((lg       ^ rx) * 8)];
      bf16x8 k1 = *(const bf16x8*)&Kt[r1*64 + (((lg + 4) ^ rx) * 8)];
      sa[nf] = __builtin_amdgcn_mfma_f32_16x16x32_bf16(k0, aq0, sa[nf], 0, 0, 0);
      sa[nf] = __builtin_amdgcn_mfma_f32_16x16x32_bf16(k1, aq1, sa[nf], 0, 0, 0);
    }
    // ---- V fragments from LDS (swizzled; ~120cyc, issued before softmax) ----
    const unsigned short* Vt = Vlds + buf*64*64;
    bf16x8 vf[4][2];
#pragma unroll
    for (int dt = 0; dt < 4; dt++) {
      int r2 = dt*16 + lr;
      vf[dt][0] = *(const bf16x8*)&Vt[r2*64 + ((lg       ^ rx) * 8)];
      vf[dt][1] = *(const bf16x8*)&Vt[r2*64 + (((lg + 4) ^ rx) * 8)];
    }
    // ---- online softmax in exp2 domain; tree max; T13 defer-max ----
    float t0 = fmaxf(fmaxf(sa[0][0], sa[0][1]), fmaxf(sa[0][2], sa[0][3]));
    float t1 = fmaxf(fmaxf(sa[1][0], sa[1][1]), fmaxf(sa[1][2], sa[1][3]));
    float t2 = fmaxf(fmaxf(sa[2][0], sa[2][1]), fmaxf(sa[2][2], sa[2][3]));
    float t3 = fmaxf(fmaxf(sa[3][0], sa[3][1]), fmaxf(sa[3][2], sa[3][3]));
    float mx = fmaxf(fmaxf(t0, t1), fmaxf(t2, t3));
    mx = fmaxf(mx, __shfl_xor(mx, 16));
    mx = fmaxf(mx, __shfl_xor(mx, 32));
    if (!__all(mx - m_ <= 8.0f)) {         // rescale only on real max growth
      float mn = fmaxf(m_, mx);
      float alpha = exp2a(m_ - mn);
      m_ = mn;
      l_ *= alpha;
#pragma unroll
      for (int dt = 0; dt < 4; dt++)
#pragma unroll
        for (int r = 0; r < 4; r++) cacc[dt][r] *= alpha;
    }
    float rsn[4];
    uint32_t u[4][2];
#pragma unroll
    for (int nf = 0; nf < 4; nf++) {
      float4v g = *(const float4v*)&gwl[key0 + nf*16 + lg*4];   // broadcast LDS read
      float p0 = exp2a(sa[nf][0] - m_) * g[0];
      float p1 = exp2a(sa[nf][1] - m_) * g[1];
      float p2 = exp2a(sa[nf][2] - m_) * g[2];
      float p3 = exp2a(sa[nf][3] - m_) * g[3];
      rsn[nf] = (p0 + p1) + (p2 + p3);
      u[nf][0] = cvtpk_bf16(p0, p1);
      u[nf][1] = cvtpk_bf16(p2, p3);
    }
    float rs = (rsn[0] + rsn[1]) + (rsn[2] + rsn[3]);
    rs += __shfl_xor(rs, 16);
    rs += __shfl_xor(rs, 32);
    l_ += rs;
    // ---- P[q=lr][key]: 4x ds_write_b64 into wave-local slab ----
#pragma unroll
    for (int nf = 0; nf < 4; nf++) {
      uint32x2 uu; uu[0] = u[nf][0]; uu[1] = u[nf][1];
      *(uint32x2*)&P[w][lr][nf*16 + lg*4] = uu;
    }
    asm volatile("s_waitcnt lgkmcnt(0)" ::: "memory");
    __builtin_amdgcn_sched_barrier(0);
    bf16x8 ap0 = *(const bf16x8*)&P[w][lr][lg*8];        // B-frag: keys 0..31
    bf16x8 ap1 = *(const bf16x8*)&P[w][lr][32 + lg*8];   // B-frag: keys 32..63
    // ---- O^T += mfma(V^T, P) ----
#pragma unroll
    for (int dt = 0; dt < 4; dt++) {
      cacc[dt] = __builtin_amdgcn_mfma_f32_16x16x32_bf16(vf[dt][0], ap0, cacc[dt], 0, 0, 0);
      cacc[dt] = __builtin_amdgcn_mfma_f32_16x16x32_bf16(vf[dt][1], ap1, cacc[dt], 0, 0, 0);
    }
    __syncthreads();   // dbuf swap: waves done reading K[t],V[t]; next stages drain here
    buf ^= 1;
  }

  // ---- epilogue: normalize, pack pairs, 4x b64 stores per lane ----
  float inv = 1.0f / l_;
  size_t row = (size_t)(b*SEQ + q0 + lr)*DIM + h*DH;
#pragma unroll
  for (int dt = 0; dt < 4; dt++) {
    uint32x2 e;
    e[0] = cvtpk_bf16(cacc[dt][0]*inv, cacc[dt][1]*inv);
    e[1] = cvtpk_bf16(cacc[dt][2]*inv, cacc[dt][3]*inv);
    *(uint32x2*)&ctx[row + dt*16 + lg*4] = e;
  }
}

// ---------------- launch ----------------
extern "C" void kernel_launch(void* const* d_in, const int* in_sizes, int n_in,
                              void* d_out, int out_size, void* d_ws, size_t ws_size,
                              hipStream_t stream) {
  const float* query = (const float*)d_in[0];
  const float* key   = (const float*)d_in[1];
  const float* value = (const float*)d_in[2];
  const int*   mask  = (const int*)d_in[3];
  const float* gauss = (const float*)d_in[4];
  const float* Wq = (const float*)d_in[5];
  const float* bq = (const float*)d_in[6];
  const float* Wk = (const float*)d_in[7];
  const float* bk = (const float*)d_in[8];
  const float* Wv = (const float*)d_in[9];
  const float* bv = (const float*)d_in[10];
  const float* Wo = (const float*)d_in[11];
  const float* bo = (const float*)d_in[12];

  char* ws = (char*)d_ws;
  const size_t MB = 1024*1024;
  unsigned short* qb  = (unsigned short*)(ws + 0*MB);   // bf16 casts of inputs (8MB each)
  unsigned short* kb  = (unsigned short*)(ws + 8*MB);
  unsigned short* vb  = (unsigned short*)(ws + 16*MB);
  unsigned short* WqT = (unsigned short*)(ws + 24*MB);  // transposed bf16 weights (2MB each)
  unsigned short* WkT = (unsigned short*)(ws + 26*MB);
  unsigned short* WvT = (unsigned short*)(ws + 28*MB);
  unsigned short* WoT = (unsigned short*)(ws + 30*MB);
  unsigned short* Qp  = (unsigned short*)(ws + 32*MB);  // projected Q (scaled*log2e), natural layout
  unsigned short* Kp  = (unsigned short*)(ws + 40*MB);  // projected K, natural layout
  unsigned short* VTb = (unsigned short*)(ws + 48*MB);  // projected V, [b][h][d][s]
  unsigned short* ctx = (unsigned short*)(ws + 56*MB);  // attention output, natural layout

  cast_qkv<<<dim3((BS*SEQ*DIM)/(256*8), 3), 256, 0, stream>>>(query, key, value, qb, kb, vb);
  wcast_t<<<dim3(DIM/32, DIM/32, 4), 256, 0, stream>>>(Wq, Wk, Wv, Wo, WqT, WkT, WvT, WoT);
  qkv_gemm<<<dim3(NWG, 3), 256, 0, stream>>>(qb, kb, vb, WqT, WkT, WvT, bq, bk, bv, Qp, Kp, VTb);
  attn<<<BS*NH*(SEQ/64), 256, 0, stream>>>(Qp, Kp, VTb, mask, gauss, ctx);
  out_gemm<<<NWG, 256, 0, stream>>>(ctx, WoT, bo, (float*)d_out);
}

// Round 15
// 114.834 us; speedup vs baseline: 2.2440x; 1.1059x over previous
//
#include <hip/hip_runtime.h>
#include <stdint.h>

#define BS 4
#define SEQ 1024
#define DIM 1024
#define NH 16
#define DH 64
#define MROWS (BS*SEQ)   // 4096

#define MT 128
#define NT 128
#define KT 32
#define NBM (MROWS/MT)   // 32
#define NBN (DIM/NT)     // 8
#define NWG (NBM*NBN)    // 256
#define NKT (DIM/KT)     // 32

typedef __attribute__((ext_vector_type(8))) short bf16x8;
typedef __attribute__((ext_vector_type(4))) float f32x4;
typedef __attribute__((ext_vector_type(8))) unsigned short ushort8;
typedef __attribute__((ext_vector_type(4))) float float4v;
typedef __attribute__((ext_vector_type(4))) int int4v;
typedef __attribute__((ext_vector_type(2))) unsigned int uint32x2;

__device__ __forceinline__ unsigned short f2bf(float x) {
  union { float f; uint32_t u; } a; a.f = x;
  uint32_t r = (a.u + 0x7FFFu + ((a.u >> 16) & 1u)) >> 16;  // RNE
  return (unsigned short)r;
}

// packed f32x2 -> bf16x2 (lo = first arg); no builtin on gfx950 -> inline asm (T12)
__device__ __forceinline__ uint32_t cvtpk_bf16(float lo, float hi) {
  uint32_t d;
  asm("v_cvt_pk_bf16_f32 %0, %1, %2" : "=v"(d) : "v"(lo), "v"(hi));
  return d;
}

// raw 2^x (softmax runs in log2 domain; log2e folded into Q scale upstream)
__device__ __forceinline__ float exp2a(float x) {
  float r;
  asm("v_exp_f32 %0, %1" : "=v"(r) : "v"(x));
  return r;
}

typedef const void __attribute__((address_space(1)))* gvp;
typedef void __attribute__((address_space(3)))* lvp;
__device__ __forceinline__ void gld_lds16(const void* g, void* l) {
  // async global->LDS, 16B/lane; LDS dest = wave-uniform base + lane*16
  __builtin_amdgcn_global_load_lds((gvp)g, (lvp)l, 16, 0, 0);
}

// ---------------- fp32 -> bf16 cast (query/key/value) ----------------
__global__ __launch_bounds__(256) void cast_qkv(
    const float* __restrict__ q, const float* __restrict__ k, const float* __restrict__ v,
    unsigned short* __restrict__ qo, unsigned short* __restrict__ ko, unsigned short* __restrict__ vo) {
  const float* s = blockIdx.y == 0 ? q : (blockIdx.y == 1 ? k : v);
  unsigned short* d = blockIdx.y == 0 ? qo : (blockIdx.y == 1 ? ko : vo);
  size_t i = ((size_t)blockIdx.x * 256 + threadIdx.x) * 8;
  float4v x0 = *(const float4v*)(s + i);
  float4v x1 = *(const float4v*)(s + i + 4);
  ushort8 r;
  r[0]=f2bf(x0[0]); r[1]=f2bf(x0[1]); r[2]=f2bf(x0[2]); r[3]=f2bf(x0[3]);
  r[4]=f2bf(x1[0]); r[5]=f2bf(x1[1]); r[6]=f2bf(x1[2]); r[7]=f2bf(x1[3]);
  *(ushort8*)(d + i) = r;
}

// ---------------- weight cast + transpose: WT[n][k] = bf16(W[k][n]) ----------------
__global__ __launch_bounds__(256) void wcast_t(
    const float* __restrict__ w0, const float* __restrict__ w1,
    const float* __restrict__ w2, const float* __restrict__ w3,
    unsigned short* __restrict__ t0, unsigned short* __restrict__ t1,
    unsigned short* __restrict__ t2, unsigned short* __restrict__ t3) {
  __shared__ float tile[32][33];
  const float* W = blockIdx.z == 0 ? w0 : blockIdx.z == 1 ? w1 : blockIdx.z == 2 ? w2 : w3;
  unsigned short* T = blockIdx.z == 0 ? t0 : blockIdx.z == 1 ? t1 : blockIdx.z == 2 ? t2 : t3;
  int tx = threadIdx.x & 31, ty = threadIdx.x >> 5;   // 32 x 8
  int bx = blockIdx.x, by = blockIdx.y;
#pragma unroll
  for (int j = 0; j < 4; j++)
    tile[ty + 8*j][tx] = W[(size_t)(by*32 + ty + 8*j)*DIM + bx*32 + tx];
  __syncthreads();
#pragma unroll
  for (int j = 0; j < 4; j++)
    T[(size_t)(bx*32 + ty + 8*j)*DIM + by*32 + tx] = f2bf(tile[tx][ty + 8*j]);
}

// ---------------- GEMM core: m97-exact 128x128 tile ----------------
// 4 waves (2x2), each computes a 64x64 sub-tile: acc[4][4], 16 MFMA/K-step.
// MODE 0: bf16 out, (acc+bias)*scale; MODE 2: bf16, per-head transposed
// VT[b][h][d][s]; MODE 3: f32 out.
template<int MODE>
__device__ __forceinline__ void gemm_core(
    unsigned short* lds,
    const unsigned short* __restrict__ A, const unsigned short* __restrict__ BT,
    const float* __restrict__ bias, void* __restrict__ outp, float scale) {
  unsigned short* Abase = lds;                 // 2 x MT*KT
  unsigned short* Bbase = lds + 2*MT*KT;       // 2 x NT*KT
  int id = blockIdx.x;
  int sw = (id & 7) * (NWG/8) + (id >> 3);     // XCD swizzle (bijective, 256%8==0)
  int bn = sw & (NBN-1), bm = sw >> 3;         // bn-fast: XCD holds 1MB A-panel + 2MB B (<L2)
  int tid = threadIdx.x, w = tid >> 6, l = tid & 63;
  int wr = w >> 1, wc = w & 1;
  int lr = l & 15, lg = l >> 4;

  auto stage = [&](int buf, int kt) {
    const unsigned short* a0 = A + (size_t)(bm*MT + w*32 + (l>>2))*DIM + kt*KT + (l&3)*8;
    gld_lds16(a0,          Abase + buf*MT*KT + (w*32)*KT);
    gld_lds16(a0 + 16*DIM, Abase + buf*MT*KT + (w*32 + 16)*KT);
    const unsigned short* b0 = BT + (size_t)(bn*NT + w*32 + (l>>2))*DIM + kt*KT + (l&3)*8;
    gld_lds16(b0,          Bbase + buf*NT*KT + (w*32)*KT);
    gld_lds16(b0 + 16*DIM, Bbase + buf*NT*KT + (w*32 + 16)*KT);
  };

  f32x4 acc[4][4] = {};
  int buf = 0;
  stage(0, 0);
  __syncthreads();
  for (int kt = 0; kt < NKT; kt++) {
    if (kt + 1 < NKT) stage(buf ^ 1, kt + 1);
    unsigned short* As = Abase + buf*MT*KT;
    unsigned short* Bs = Bbase + buf*NT*KT;
    bf16x8 af[4], bf_[4];
#pragma unroll
    for (int mi = 0; mi < 4; mi++)
      af[mi] = *(const bf16x8*)&As[(wr*64 + mi*16 + lr)*KT + lg*8];
#pragma unroll
    for (int ni = 0; ni < 4; ni++)
      bf_[ni] = *(const bf16x8*)&Bs[(wc*64 + ni*16 + lr)*KT + lg*8];
#pragma unroll
    for (int mi = 0; mi < 4; mi++)
#pragma unroll
      for (int ni = 0; ni < 4; ni++)
        acc[mi][ni] = __builtin_amdgcn_mfma_f32_16x16x32_bf16(af[mi], bf_[ni], acc[mi][ni], 0, 0, 0);
    __syncthreads();   // drains vmcnt for the staged next tile + protects buffer reuse
    buf ^= 1;
  }

  int row0 = bm*MT + wr*64;
  int col0 = bn*NT + wc*64;
#pragma unroll
  for (int ni = 0; ni < 4; ni++) {
    int col = col0 + ni*16 + lr;
    float bv = bias[col];
#pragma unroll
    for (int mi = 0; mi < 4; mi++)
#pragma unroll
      for (int r = 0; r < 4; r++) {
        int row = row0 + mi*16 + lg*4 + r;
        float val = acc[mi][ni][r] + bv;
        if (MODE == 0) {
          ((unsigned short*)outp)[(size_t)row*DIM + col] = f2bf(val * scale);
        } else if (MODE == 2) {
          int b = row >> 10, s = row & 1023, h = col >> 6, d = col & 63;
          ((unsigned short*)outp)[(size_t)((b*NH + h)*DH + d)*SEQ + s] = f2bf(val);
        } else {
          ((float*)outp)[(size_t)row*DIM + col] = val;
        }
      }
  }
}

__global__ __launch_bounds__(256) void qkv_gemm(
    const unsigned short* __restrict__ qb, const unsigned short* __restrict__ kb,
    const unsigned short* __restrict__ vb,
    const unsigned short* __restrict__ WqT, const unsigned short* __restrict__ WkT,
    const unsigned short* __restrict__ WvT,
    const float* __restrict__ bq, const float* __restrict__ bk, const float* __restrict__ bv,
    unsigned short* __restrict__ Qp, unsigned short* __restrict__ Kp,
    unsigned short* __restrict__ VT) {
  __shared__ __align__(16) unsigned short lds[2*(MT+NT)*KT];
  int z = blockIdx.y;
  // Q scale = 1/sqrt(64) * log2(e): softmax runs in exp2 domain downstream
  if (z == 0)      gemm_core<0>(lds, qb, WqT, bq, Qp, 0.18033688011112042f);
  else if (z == 1) gemm_core<0>(lds, kb, WkT, bk, Kp, 1.0f);
  else             gemm_core<2>(lds, vb, WvT, bv, VT, 1.0f);
}

__global__ __launch_bounds__(256) void out_gemm(
    const unsigned short* __restrict__ ctx, const unsigned short* __restrict__ WoT,
    const float* __restrict__ bo, float* __restrict__ out) {
  __shared__ __align__(16) unsigned short lds[2*(MT+NT)*KT];
  gemm_core<3>(lds, ctx, WoT, bo, out, 1.0f);
}

// ---------------- flash attention (R14 champion, 8-wave blocks) ----------------
// Block = 8 waves x 16 q-rows = 128 q-rows; grid 512 = exactly 2 blocks/CU ->
// 16 resident waves/CU (vs R14's 12 at 3 blocks/CU, Occupancy 23%) with zero
// scheduling tail. K/V LDS tiles shared by 8 waves instead of 4: per-CU stage
// DMA halves (each wave issues exactly ONE gld_lds16 per tile per buffer).
// Per-iteration schedule is R14-exact: K+V zero-VGPR global_load_lds double
// buffers (XOR-swizzled, both-sides rule), swapped QK^T (lane owns q-row lr ->
// per-lane scalar softmax), exp2 domain, T13 defer-max, wave-local P slab with
// manual lgkmcnt fence, single end-of-iter barrier draining next-tile stages.
__global__ __launch_bounds__(512, 4) void attn(
    const unsigned short* __restrict__ Qp, const unsigned short* __restrict__ Kp,
    const unsigned short* __restrict__ VT, const int* __restrict__ mask,
    const float* __restrict__ gauss, unsigned short* __restrict__ ctx) {
  __shared__ __align__(16) unsigned short Klds[2*64*64];  // 16KB double-buffered K tile
  __shared__ __align__(16) unsigned short Vlds[2*64*64];  // 16KB double-buffered V tile
  __shared__ __align__(16) unsigned short P[8][16][72];   // 18KB: per-wave slabs, padded
  __shared__ float gwl[SEQ];                              // mask-folded gauss weights
  int blk = blockIdx.x;
  int bh = blk & 63, qt = blk >> 6;        // head-major: head bh pinned to XCD bh%8
  int b = bh >> 4, h = bh & 15;
  int tid = threadIdx.x, w = tid >> 6, l = tid & 63;
  int lr = l & 15, lg = l >> 4;
  int q0 = qt*128 + w*16;                  // 8 waves cover 128 q-rows

  // ---- stash mask-folded gauss row in LDS (512 threads x 2 elems) ----
  {
    int i2 = tid * 2;
    gwl[i2]     = mask[b*SEQ + i2]     ? gauss[b*SEQ + i2]     + 1e-10f : 0.f;
    gwl[i2 + 1] = mask[b*SEQ + i2 + 1] ? gauss[b*SEQ + i2 + 1] + 1e-10f : 0.f;
  }

  const unsigned short* Qb = Qp + (size_t)(b*SEQ + q0 + lr)*DIM + h*DH + lg*8;
  bf16x8 aq0 = *(const bf16x8*)Qb;
  bf16x8 aq1 = *(const bf16x8*)(Qb + 32);

  float m_ = -1e30f, l_ = 0.f;             // per-lane scalars (q = lr), log2 domain
  f32x4 cacc[4] = {};                      // O^T[d = dt*16+lg*4+r][q = lr]

  const unsigned short* Krow0 = Kp + (size_t)(b*SEQ)*DIM + h*DH;   // key-rows, stride DIM
  const unsigned short* Vrow0 = VT + (size_t)((b*NH + h)*DH)*SEQ;  // d-rows, stride SEQ

  // staging geometry: per instr, lane l covers row (l>>3), 16B slot (l&7);
  // source slot pre-swizzled by row&7 (both-sides swizzle rule). 8 waves x
  // 8 rows = 64-row tile: exactly one gld_lds16 per wave per buffer.
  int srow = l >> 3;
  int scol = ((l & 7) ^ srow) * 8;
  auto stageK = [&](int buf, int key0) {
    gld_lds16(Krow0 + (size_t)(key0 + w*8 + srow)*DIM + scol, Klds + buf*64*64 + (w*8)*64);
  };
  auto stageV = [&](int buf, int key0) {
    gld_lds16(Vrow0 + (size_t)(w*8 + srow)*SEQ + key0 + scol, Vlds + buf*64*64 + (w*8)*64);
  };

  stageK(0, 0);
  stageV(0, 0);
  __syncthreads();   // gwl + K[0] + V[0] ready
  int buf = 0;
  int rx = lr & 7;   // swizzle index: (row&7) for all rows read below
  for (int kt = 0; kt < 16; kt++) {
    int key0 = kt*64;
    // ---- issue next K+V stages (async DMA, zero VGPR; drained by end-of-iter barrier) ----
    if (kt < 15) { stageK(buf ^ 1, key0 + 64); stageV(buf ^ 1, key0 + 64); }
    // ---- S^T = mfma(K, Q) from LDS (swizzled read): sa[nf][r] = S[key][q=lr] ----
    const unsigned short* Kt = Klds + buf*64*64;
    f32x4 sa[4] = {};
#pragma unroll
    for (int nf = 0; nf < 4; nf++) {
      int r1 = nf*16 + lr;
      bf16x8 k0 = *(const bf16x8*)&Kt[r1*64 + ((lg       ^ rx) * 8)];
      bf16x8 k1 = *(const bf16x8*)&Kt[r1*64 + (((lg + 4) ^ rx) * 8)];
      sa[nf] = __builtin_amdgcn_mfma_f32_16x16x32_bf16(k0, aq0, sa[nf], 0, 0, 0);
      sa[nf] = __builtin_amdgcn_mfma_f32_16x16x32_bf16(k1, aq1, sa[nf], 0, 0, 0);
    }
    // ---- V fragments from LDS (swizzled; ~120cyc, issued before softmax) ----
    const unsigned short* Vt = Vlds + buf*64*64;
    bf16x8 vf[4][2];
#pragma unroll
    for (int dt = 0; dt < 4; dt++) {
      int r2 = dt*16 + lr;
      vf[dt][0] = *(const bf16x8*)&Vt[r2*64 + ((lg       ^ rx) * 8)];
      vf[dt][1] = *(const bf16x8*)&Vt[r2*64 + (((lg + 4) ^ rx) * 8)];
    }
    // ---- online softmax in exp2 domain; tree max; T13 defer-max ----
    float t0 = fmaxf(fmaxf(sa[0][0], sa[0][1]), fmaxf(sa[0][2], sa[0][3]));
    float t1 = fmaxf(fmaxf(sa[1][0], sa[1][1]), fmaxf(sa[1][2], sa[1][3]));
    float t2 = fmaxf(fmaxf(sa[2][0], sa[2][1]), fmaxf(sa[2][2], sa[2][3]));
    float t3 = fmaxf(fmaxf(sa[3][0], sa[3][1]), fmaxf(sa[3][2], sa[3][3]));
    float mx = fmaxf(fmaxf(t0, t1), fmaxf(t2, t3));
    mx = fmaxf(mx, __shfl_xor(mx, 16));
    mx = fmaxf(mx, __shfl_xor(mx, 32));
    if (!__all(mx - m_ <= 8.0f)) {         // rescale only on real max growth
      float mn = fmaxf(m_, mx);
      float alpha = exp2a(m_ - mn);
      m_ = mn;
      l_ *= alpha;
#pragma unroll
      for (int dt = 0; dt < 4; dt++)
#pragma unroll
        for (int r = 0; r < 4; r++) cacc[dt][r] *= alpha;
    }
    float rsn[4];
    uint32_t u[4][2];
#pragma unroll
    for (int nf = 0; nf < 4; nf++) {
      float4v g = *(const float4v*)&gwl[key0 + nf*16 + lg*4];   // broadcast LDS read
      float p0 = exp2a(sa[nf][0] - m_) * g[0];
      float p1 = exp2a(sa[nf][1] - m_) * g[1];
      float p2 = exp2a(sa[nf][2] - m_) * g[2];
      float p3 = exp2a(sa[nf][3] - m_) * g[3];
      rsn[nf] = (p0 + p1) + (p2 + p3);
      u[nf][0] = cvtpk_bf16(p0, p1);
      u[nf][1] = cvtpk_bf16(p2, p3);
    }
    float rs = (rsn[0] + rsn[1]) + (rsn[2] + rsn[3]);
    rs += __shfl_xor(rs, 16);
    rs += __shfl_xor(rs, 32);
    l_ += rs;
    // ---- P[q=lr][key]: 4x ds_write_b64 into wave-local slab ----
#pragma unroll
    for (int nf = 0; nf < 4; nf++) {
      uint32x2 uu; uu[0] = u[nf][0]; uu[1] = u[nf][1];
      *(uint32x2*)&P[w][lr][nf*16 + lg*4] = uu;
    }
    asm volatile("s_waitcnt lgkmcnt(0)" ::: "memory");
    __builtin_amdgcn_sched_barrier(0);
    bf16x8 ap0 = *(const bf16x8*)&P[w][lr][lg*8];        // B-frag: keys 0..31
    bf16x8 ap1 = *(const bf16x8*)&P[w][lr][32 + lg*8];   // B-frag: keys 32..63
    // ---- O^T += mfma(V^T, P) ----
#pragma unroll
    for (int dt = 0; dt < 4; dt++) {
      cacc[dt] = __builtin_amdgcn_mfma_f32_16x16x32_bf16(vf[dt][0], ap0, cacc[dt], 0, 0, 0);
      cacc[dt] = __builtin_amdgcn_mfma_f32_16x16x32_bf16(vf[dt][1], ap1, cacc[dt], 0, 0, 0);
    }
    __syncthreads();   // dbuf swap: waves done reading K[t],V[t]; next stages drain here
    buf ^= 1;
  }

  // ---- epilogue: normalize, pack pairs, 4x b64 stores per lane ----
  float inv = 1.0f / l_;
  size_t row = (size_t)(b*SEQ + q0 + lr)*DIM + h*DH;
#pragma unroll
  for (int dt = 0; dt < 4; dt++) {
    uint32x2 e;
    e[0] = cvtpk_bf16(cacc[dt][0]*inv, cacc[dt][1]*inv);
    e[1] = cvtpk_bf16(cacc[dt][2]*inv, cacc[dt][3]*inv);
    *(uint32x2*)&ctx[row + dt*16 + lg*4] = e;
  }
}

// ---------------- launch ----------------
extern "C" void kernel_launch(void* const* d_in, const int* in_sizes, int n_in,
                              void* d_out, int out_size, void* d_ws, size_t ws_size,
                              hipStream_t stream) {
  const float* query = (const float*)d_in[0];
  const float* key   = (const float*)d_in[1];
  const float* value = (const float*)d_in[2];
  const int*   mask  = (const int*)d_in[3];
  const float* gauss = (const float*)d_in[4];
  const float* Wq = (const float*)d_in[5];
  const float* bq = (const float*)d_in[6];
  const float* Wk = (const float*)d_in[7];
  const float* bk = (const float*)d_in[8];
  const float* Wv = (const float*)d_in[9];
  const float* bv = (const float*)d_in[10];
  const float* Wo = (const float*)d_in[11];
  const float* bo = (const float*)d_in[12];

  char* ws = (char*)d_ws;
  const size_t MB = 1024*1024;
  unsigned short* qb  = (unsigned short*)(ws + 0*MB);   // bf16 casts of inputs (8MB each)
  unsigned short* kb  = (unsigned short*)(ws + 8*MB);
  unsigned short* vb  = (unsigned short*)(ws + 16*MB);
  unsigned short* WqT = (unsigned short*)(ws + 24*MB);  // transposed bf16 weights (2MB each)
  unsigned short* WkT = (unsigned short*)(ws + 26*MB);
  unsigned short* WvT = (unsigned short*)(ws + 28*MB);
  unsigned short* WoT = (unsigned short*)(ws + 30*MB);
  unsigned short* Qp  = (unsigned short*)(ws + 32*MB);  // projected Q (scaled*log2e), natural layout
  unsigned short* Kp  = (unsigned short*)(ws + 40*MB);  // projected K, natural layout
  unsigned short* VTb = (unsigned short*)(ws + 48*MB);  // projected V, [b][h][d][s]
  unsigned short* ctx = (unsigned short*)(ws + 56*MB);  // attention output, natural layout

  cast_qkv<<<dim3((BS*SEQ*DIM)/(256*8), 3), 256, 0, stream>>>(query, key, value, qb, kb, vb);
  wcast_t<<<dim3(DIM/32, DIM/32, 4), 256, 0, stream>>>(Wq, Wk, Wv, Wo, WqT, WkT, WvT, WoT);
  qkv_gemm<<<dim3(NWG, 3), 256, 0, stream>>>(qb, kb, vb, WqT, WkT, WvT, bq, bk, bv, Qp, Kp, VTb);
  attn<<<BS*NH*(SEQ/128), 512, 0, stream>>>(Qp, Kp, VTb, mask, gauss, ctx);
  out_gemm<<<NWG, 256, 0, stream>>>(ctx, WoT, bo, (float*)d_out);
}

// Round 16
// 113.039 us; speedup vs baseline: 2.2797x; 1.0159x over previous
//
#include <hip/hip_runtime.h>
#include <stdint.h>

#define BS 4
#define SEQ 1024
#define DIM 1024
#define NH 16
#define DH 64
#define MROWS (BS*SEQ)   // 4096

#define MT 128
#define NT 128
#define KT 32
#define NBM (MROWS/MT)   // 32
#define NBN (DIM/NT)     // 8
#define NWG (NBM*NBN)    // 256
#define NKT (DIM/KT)     // 32

typedef __attribute__((ext_vector_type(8))) short bf16x8;
typedef __attribute__((ext_vector_type(4))) float f32x4;
typedef __attribute__((ext_vector_type(8))) unsigned short ushort8;
typedef __attribute__((ext_vector_type(4))) float float4v;
typedef __attribute__((ext_vector_type(4))) int int4v;
typedef __attribute__((ext_vector_type(2))) unsigned int uint32x2;

__device__ __forceinline__ unsigned short f2bf(float x) {
  union { float f; uint32_t u; } a; a.f = x;
  uint32_t r = (a.u + 0x7FFFu + ((a.u >> 16) & 1u)) >> 16;  // RNE
  return (unsigned short)r;
}

// packed f32x2 -> bf16x2 (lo = first arg); no builtin on gfx950 -> inline asm (T12)
__device__ __forceinline__ uint32_t cvtpk_bf16(float lo, float hi) {
  uint32_t d;
  asm("v_cvt_pk_bf16_f32 %0, %1, %2" : "=v"(d) : "v"(lo), "v"(hi));
  return d;
}

// raw 2^x (softmax runs in log2 domain; log2e folded into Q scale upstream)
__device__ __forceinline__ float exp2a(float x) {
  float r;
  asm("v_exp_f32 %0, %1" : "=v"(r) : "v"(x));
  return r;
}

typedef const void __attribute__((address_space(1)))* gvp;
typedef void __attribute__((address_space(3)))* lvp;
__device__ __forceinline__ void gld_lds16(const void* g, void* l) {
  // async global->LDS, 16B/lane; LDS dest = wave-uniform base + lane*16
  __builtin_amdgcn_global_load_lds((gvp)g, (lvp)l, 16, 0, 0);
}

// ---------------- fp32 -> bf16 cast (query/key/value) ----------------
__global__ __launch_bounds__(256) void cast_qkv(
    const float* __restrict__ q, const float* __restrict__ k, const float* __restrict__ v,
    unsigned short* __restrict__ qo, unsigned short* __restrict__ ko, unsigned short* __restrict__ vo) {
  const float* s = blockIdx.y == 0 ? q : (blockIdx.y == 1 ? k : v);
  unsigned short* d = blockIdx.y == 0 ? qo : (blockIdx.y == 1 ? ko : vo);
  size_t i = ((size_t)blockIdx.x * 256 + threadIdx.x) * 8;
  float4v x0 = *(const float4v*)(s + i);
  float4v x1 = *(const float4v*)(s + i + 4);
  ushort8 r;
  r[0]=f2bf(x0[0]); r[1]=f2bf(x0[1]); r[2]=f2bf(x0[2]); r[3]=f2bf(x0[3]);
  r[4]=f2bf(x1[0]); r[5]=f2bf(x1[1]); r[6]=f2bf(x1[2]); r[7]=f2bf(x1[3]);
  *(ushort8*)(d + i) = r;
}

// ---------------- weight cast + transpose: WT[n][k] = bf16(W[k][n]) ----------------
__global__ __launch_bounds__(256) void wcast_t(
    const float* __restrict__ w0, const float* __restrict__ w1,
    const float* __restrict__ w2, const float* __restrict__ w3,
    unsigned short* __restrict__ t0, unsigned short* __restrict__ t1,
    unsigned short* __restrict__ t2, unsigned short* __restrict__ t3) {
  __shared__ float tile[32][33];
  const float* W = blockIdx.z == 0 ? w0 : blockIdx.z == 1 ? w1 : blockIdx.z == 2 ? w2 : w3;
  unsigned short* T = blockIdx.z == 0 ? t0 : blockIdx.z == 1 ? t1 : blockIdx.z == 2 ? t2 : t3;
  int tx = threadIdx.x & 31, ty = threadIdx.x >> 5;   // 32 x 8
  int bx = blockIdx.x, by = blockIdx.y;
#pragma unroll
  for (int j = 0; j < 4; j++)
    tile[ty + 8*j][tx] = W[(size_t)(by*32 + ty + 8*j)*DIM + bx*32 + tx];
  __syncthreads();
#pragma unroll
  for (int j = 0; j < 4; j++)
    T[(size_t)(bx*32 + ty + 8*j)*DIM + by*32 + tx] = f2bf(tile[tx][ty + 8*j]);
}

// ---------------- GEMM core: m97-exact 128x128 tile ----------------
// 4 waves (2x2), each computes a 64x64 sub-tile: acc[4][4], 16 MFMA/K-step.
// MODE 0: bf16 out, (acc+bias)*scale; MODE 2: bf16, per-head transposed
// VT[b][h][d][s] with PACKED b64 stores (r=0..3 = consecutive rows = consecutive
// s in VT -> contiguous 8B; was 64 scalar 2B stores at 2KB stride, the z=2 tail
// that gated qkv_gemm); MODE 3: f32 out.
template<int MODE>
__device__ __forceinline__ void gemm_core(
    unsigned short* lds,
    const unsigned short* __restrict__ A, const unsigned short* __restrict__ BT,
    const float* __restrict__ bias, void* __restrict__ outp, float scale) {
  unsigned short* Abase = lds;                 // 2 x MT*KT
  unsigned short* Bbase = lds + 2*MT*KT;       // 2 x NT*KT
  int id = blockIdx.x;
  int sw = (id & 7) * (NWG/8) + (id >> 3);     // XCD swizzle (bijective, 256%8==0)
  int bn = sw & (NBN-1), bm = sw >> 3;         // bn-fast: XCD holds 1MB A-panel + 2MB B (<L2)
  int tid = threadIdx.x, w = tid >> 6, l = tid & 63;
  int wr = w >> 1, wc = w & 1;
  int lr = l & 15, lg = l >> 4;

  auto stage = [&](int buf, int kt) {
    const unsigned short* a0 = A + (size_t)(bm*MT + w*32 + (l>>2))*DIM + kt*KT + (l&3)*8;
    gld_lds16(a0,          Abase + buf*MT*KT + (w*32)*KT);
    gld_lds16(a0 + 16*DIM, Abase + buf*MT*KT + (w*32 + 16)*KT);
    const unsigned short* b0 = BT + (size_t)(bn*NT + w*32 + (l>>2))*DIM + kt*KT + (l&3)*8;
    gld_lds16(b0,          Bbase + buf*NT*KT + (w*32)*KT);
    gld_lds16(b0 + 16*DIM, Bbase + buf*NT*KT + (w*32 + 16)*KT);
  };

  f32x4 acc[4][4] = {};
  int buf = 0;
  stage(0, 0);
  __syncthreads();
  for (int kt = 0; kt < NKT; kt++) {
    if (kt + 1 < NKT) stage(buf ^ 1, kt + 1);
    unsigned short* As = Abase + buf*MT*KT;
    unsigned short* Bs = Bbase + buf*NT*KT;
    bf16x8 af[4], bf_[4];
#pragma unroll
    for (int mi = 0; mi < 4; mi++)
      af[mi] = *(const bf16x8*)&As[(wr*64 + mi*16 + lr)*KT + lg*8];
#pragma unroll
    for (int ni = 0; ni < 4; ni++)
      bf_[ni] = *(const bf16x8*)&Bs[(wc*64 + ni*16 + lr)*KT + lg*8];
#pragma unroll
    for (int mi = 0; mi < 4; mi++)
#pragma unroll
      for (int ni = 0; ni < 4; ni++)
        acc[mi][ni] = __builtin_amdgcn_mfma_f32_16x16x32_bf16(af[mi], bf_[ni], acc[mi][ni], 0, 0, 0);
    __syncthreads();   // drains vmcnt for the staged next tile + protects buffer reuse
    buf ^= 1;
  }

  int row0 = bm*MT + wr*64;
  int col0 = bn*NT + wc*64;
#pragma unroll
  for (int ni = 0; ni < 4; ni++) {
    int col = col0 + ni*16 + lr;
    float bv = bias[col];
#pragma unroll
    for (int mi = 0; mi < 4; mi++) {
      if (MODE == 2) {
        // packed: 4 consecutive rows -> 4 consecutive s -> one b64 store
        int row = row0 + mi*16 + lg*4;
        int b = row >> 10, s = row & 1023, h = col >> 6, d = col & 63;
        uint32x2 e;
        e[0] = cvtpk_bf16(acc[mi][ni][0] + bv, acc[mi][ni][1] + bv);
        e[1] = cvtpk_bf16(acc[mi][ni][2] + bv, acc[mi][ni][3] + bv);
        *(uint32x2*)&((unsigned short*)outp)[(size_t)((b*NH + h)*DH + d)*SEQ + s] = e;
      } else {
#pragma unroll
        for (int r = 0; r < 4; r++) {
          int row = row0 + mi*16 + lg*4 + r;
          float val = acc[mi][ni][r] + bv;
          if (MODE == 0) {
            ((unsigned short*)outp)[(size_t)row*DIM + col] = f2bf(val * scale);
          } else {
            ((float*)outp)[(size_t)row*DIM + col] = val;
          }
        }
      }
    }
  }
}

__global__ __launch_bounds__(256) void qkv_gemm(
    const unsigned short* __restrict__ qb, const unsigned short* __restrict__ kb,
    const unsigned short* __restrict__ vb,
    const unsigned short* __restrict__ WqT, const unsigned short* __restrict__ WkT,
    const unsigned short* __restrict__ WvT,
    const float* __restrict__ bq, const float* __restrict__ bk, const float* __restrict__ bv,
    unsigned short* __restrict__ Qp, unsigned short* __restrict__ Kp,
    unsigned short* __restrict__ VT) {
  __shared__ __align__(16) unsigned short lds[2*(MT+NT)*KT];
  int z = blockIdx.y;
  // Q scale = 1/sqrt(64) * log2(e): softmax runs in exp2 domain downstream
  if (z == 0)      gemm_core<0>(lds, qb, WqT, bq, Qp, 0.18033688011112042f);
  else if (z == 1) gemm_core<0>(lds, kb, WkT, bk, Kp, 1.0f);
  else             gemm_core<2>(lds, vb, WvT, bv, VT, 1.0f);
}

__global__ __launch_bounds__(256) void out_gemm(
    const unsigned short* __restrict__ ctx, const unsigned short* __restrict__ WoT,
    const float* __restrict__ bo, float* __restrict__ out) {
  __shared__ __align__(16) unsigned short lds[2*(MT+NT)*KT];
  gemm_core<3>(lds, ctx, WoT, bo, out, 1.0f);
}

// ---------------- flash attention (R15 champion + T5 setprio) ----------------
// Block = 8 waves x 16 q-rows = 128 q-rows; grid 512 = exactly 2 blocks/CU ->
// 16 resident waves/CU. Residency is GRID-capped (2 blocks/CU regardless of
// LDS), so the remaining lever is scheduler arbitration: 2 independent blocks
// per CU = wave role diversity -> T5 s_setprio(1) around the MFMA clusters
// (m191 regime: +4-7%; null only in single-block lockstep, m190).
// Mechanics (proven R14/R15): K+V zero-VGPR global_load_lds double buffers
// (XOR-swizzled, both-sides rule), swapped QK^T (lane owns q-row lr -> per-lane
// scalar softmax), exp2 domain, T13 defer-max, wave-local P slab with manual
// lgkmcnt fence, single end-of-iter barrier draining next-tile stages.
__global__ __launch_bounds__(512, 4) void attn(
    const unsigned short* __restrict__ Qp, const unsigned short* __restrict__ Kp,
    const unsigned short* __restrict__ VT, const int* __restrict__ mask,
    const float* __restrict__ gauss, unsigned short* __restrict__ ctx) {
  __shared__ __align__(16) unsigned short Klds[2*64*64];  // 16KB double-buffered K tile
  __shared__ __align__(16) unsigned short Vlds[2*64*64];  // 16KB double-buffered V tile
  __shared__ __align__(16) unsigned short P[8][16][72];   // 18KB: per-wave slabs, padded
  __shared__ float gwl[SEQ];                              // mask-folded gauss weights
  int blk = blockIdx.x;
  int bh = blk & 63, qt = blk >> 6;        // head-major: head bh pinned to XCD bh%8
  int b = bh >> 4, h = bh & 15;
  int tid = threadIdx.x, w = tid >> 6, l = tid & 63;
  int lr = l & 15, lg = l >> 4;
  int q0 = qt*128 + w*16;                  // 8 waves cover 128 q-rows

  // ---- stash mask-folded gauss row in LDS (512 threads x 2 elems) ----
  {
    int i2 = tid * 2;
    gwl[i2]     = mask[b*SEQ + i2]     ? gauss[b*SEQ + i2]     + 1e-10f : 0.f;
    gwl[i2 + 1] = mask[b*SEQ + i2 + 1] ? gauss[b*SEQ + i2 + 1] + 1e-10f : 0.f;
  }

  const unsigned short* Qb = Qp + (size_t)(b*SEQ + q0 + lr)*DIM + h*DH + lg*8;
  bf16x8 aq0 = *(const bf16x8*)Qb;
  bf16x8 aq1 = *(const bf16x8*)(Qb + 32);

  float m_ = -1e30f, l_ = 0.f;             // per-lane scalars (q = lr), log2 domain
  f32x4 cacc[4] = {};                      // O^T[d = dt*16+lg*4+r][q = lr]

  const unsigned short* Krow0 = Kp + (size_t)(b*SEQ)*DIM + h*DH;   // key-rows, stride DIM
  const unsigned short* Vrow0 = VT + (size_t)((b*NH + h)*DH)*SEQ;  // d-rows, stride SEQ

  // staging geometry: per instr, lane l covers row (l>>3), 16B slot (l&7);
  // source slot pre-swizzled by row&7 (both-sides swizzle rule). 8 waves x
  // 8 rows = 64-row tile: exactly one gld_lds16 per wave per buffer.
  int srow = l >> 3;
  int scol = ((l & 7) ^ srow) * 8;
  auto stageK = [&](int buf, int key0) {
    gld_lds16(Krow0 + (size_t)(key0 + w*8 + srow)*DIM + scol, Klds + buf*64*64 + (w*8)*64);
  };
  auto stageV = [&](int buf, int key0) {
    gld_lds16(Vrow0 + (size_t)(w*8 + srow)*SEQ + key0 + scol, Vlds + buf*64*64 + (w*8)*64);
  };

  stageK(0, 0);
  stageV(0, 0);
  __syncthreads();   // gwl + K[0] + V[0] ready
  int buf = 0;
  int rx = lr & 7;   // swizzle index: (row&7) for all rows read below
  for (int kt = 0; kt < 16; kt++) {
    int key0 = kt*64;
    // ---- issue next K+V stages (async DMA, zero VGPR; drained by end-of-iter barrier) ----
    if (kt < 15) { stageK(buf ^ 1, key0 + 64); stageV(buf ^ 1, key0 + 64); }
    // ---- S^T = mfma(K, Q) from LDS (swizzled read): sa[nf][r] = S[key][q=lr] ----
    const unsigned short* Kt = Klds + buf*64*64;
    f32x4 sa[4] = {};
    __builtin_amdgcn_s_setprio(1);
#pragma unroll
    for (int nf = 0; nf < 4; nf++) {
      int r1 = nf*16 + lr;
      bf16x8 k0 = *(const bf16x8*)&Kt[r1*64 + ((lg       ^ rx) * 8)];
      bf16x8 k1 = *(const bf16x8*)&Kt[r1*64 + (((lg + 4) ^ rx) * 8)];
      sa[nf] = __builtin_amdgcn_mfma_f32_16x16x32_bf16(k0, aq0, sa[nf], 0, 0, 0);
      sa[nf] = __builtin_amdgcn_mfma_f32_16x16x32_bf16(k1, aq1, sa[nf], 0, 0, 0);
    }
    __builtin_amdgcn_s_setprio(0);
    // ---- V fragments from LDS (swizzled; ~120cyc, issued before softmax) ----
    const unsigned short* Vt = Vlds + buf*64*64;
    bf16x8 vf[4][2];
#pragma unroll
    for (int dt = 0; dt < 4; dt++) {
      int r2 = dt*16 + lr;
      vf[dt][0] = *(const bf16x8*)&Vt[r2*64 + ((lg       ^ rx) * 8)];
      vf[dt][1] = *(const bf16x8*)&Vt[r2*64 + (((lg + 4) ^ rx) * 8)];
    }
    // ---- online softmax in exp2 domain; tree max; T13 defer-max ----
    float t0 = fmaxf(fmaxf(sa[0][0], sa[0][1]), fmaxf(sa[0][2], sa[0][3]));
    float t1 = fmaxf(fmaxf(sa[1][0], sa[1][1]), fmaxf(sa[1][2], sa[1][3]));
    float t2 = fmaxf(fmaxf(sa[2][0], sa[2][1]), fmaxf(sa[2][2], sa[2][3]));
    float t3 = fmaxf(fmaxf(sa[3][0], sa[3][1]), fmaxf(sa[3][2], sa[3][3]));
    float mx = fmaxf(fmaxf(t0, t1), fmaxf(t2, t3));
    mx = fmaxf(mx, __shfl_xor(mx, 16));
    mx = fmaxf(mx, __shfl_xor(mx, 32));
    if (!__all(mx - m_ <= 8.0f)) {         // rescale only on real max growth
      float mn = fmaxf(m_, mx);
      float alpha = exp2a(m_ - mn);
      m_ = mn;
      l_ *= alpha;
#pragma unroll
      for (int dt = 0; dt < 4; dt++)
#pragma unroll
        for (int r = 0; r < 4; r++) cacc[dt][r] *= alpha;
    }
    float rsn[4];
    uint32_t u[4][2];
#pragma unroll
    for (int nf = 0; nf < 4; nf++) {
      float4v g = *(const float4v*)&gwl[key0 + nf*16 + lg*4];   // broadcast LDS read
      float p0 = exp2a(sa[nf][0] - m_) * g[0];
      float p1 = exp2a(sa[nf][1] - m_) * g[1];
      float p2 = exp2a(sa[nf][2] - m_) * g[2];
      float p3 = exp2a(sa[nf][3] - m_) * g[3];
      rsn[nf] = (p0 + p1) + (p2 + p3);
      u[nf][0] = cvtpk_bf16(p0, p1);
      u[nf][1] = cvtpk_bf16(p2, p3);
    }
    float rs = (rsn[0] + rsn[1]) + (rsn[2] + rsn[3]);
    rs += __shfl_xor(rs, 16);
    rs += __shfl_xor(rs, 32);
    l_ += rs;
    // ---- P[q=lr][key]: 4x ds_write_b64 into wave-local slab ----
#pragma unroll
    for (int nf = 0; nf < 4; nf++) {
      uint32x2 uu; uu[0] = u[nf][0]; uu[1] = u[nf][1];
      *(uint32x2*)&P[w][lr][nf*16 + lg*4] = uu;
    }
    asm volatile("s_waitcnt lgkmcnt(0)" ::: "memory");
    __builtin_amdgcn_sched_barrier(0);
    bf16x8 ap0 = *(const bf16x8*)&P[w][lr][lg*8];        // B-frag: keys 0..31
    bf16x8 ap1 = *(const bf16x8*)&P[w][lr][32 + lg*8];   // B-frag: keys 32..63
    // ---- O^T += mfma(V^T, P) ----
    __builtin_amdgcn_s_setprio(1);
#pragma unroll
    for (int dt = 0; dt < 4; dt++) {
      cacc[dt] = __builtin_amdgcn_mfma_f32_16x16x32_bf16(vf[dt][0], ap0, cacc[dt], 0, 0, 0);
      cacc[dt] = __builtin_amdgcn_mfma_f32_16x16x32_bf16(vf[dt][1], ap1, cacc[dt], 0, 0, 0);
    }
    __builtin_amdgcn_s_setprio(0);
    __syncthreads();   // dbuf swap: waves done reading K[t],V[t]; next stages drain here
    buf ^= 1;
  }

  // ---- epilogue: normalize, pack pairs, 4x b64 stores per lane ----
  float inv = 1.0f / l_;
  size_t row = (size_t)(b*SEQ + q0 + lr)*DIM + h*DH;
#pragma unroll
  for (int dt = 0; dt < 4; dt++) {
    uint32x2 e;
    e[0] = cvtpk_bf16(cacc[dt][0]*inv, cacc[dt][1]*inv);
    e[1] = cvtpk_bf16(cacc[dt][2]*inv, cacc[dt][3]*inv);
    *(uint32x2*)&ctx[row + dt*16 + lg*4] = e;
  }
}

// ---------------- launch ----------------
extern "C" void kernel_launch(void* const* d_in, const int* in_sizes, int n_in,
                              void* d_out, int out_size, void* d_ws, size_t ws_size,
                              hipStream_t stream) {
  const float* query = (const float*)d_in[0];
  const float* key   = (const float*)d_in[1];
  const float* value = (const float*)d_in[2];
  const int*   mask  = (const int*)d_in[3];
  const float* gauss = (const float*)d_in[4];
  const float* Wq = (const float*)d_in[5];
  const float* bq = (const float*)d_in[6];
  const float* Wk = (const float*)d_in[7];
  const float* bk = (const float*)d_in[8];
  const float* Wv = (const float*)d_in[9];
  const float* bv = (const float*)d_in[10];
  const float* Wo = (const float*)d_in[11];
  const float* bo = (const float*)d_in[12];

  char* ws = (char*)d_ws;
  const size_t MB = 1024*1024;
  unsigned short* qb  = (unsigned short*)(ws + 0*MB);   // bf16 casts of inputs (8MB each)
  unsigned short* kb  = (unsigned short*)(ws + 8*MB);
  unsigned short* vb  = (unsigned short*)(ws + 16*MB);
  unsigned short* WqT = (unsigned short*)(ws + 24*MB);  // transposed bf16 weights (2MB each)
  unsigned short* WkT = (unsigned short*)(ws + 26*MB);
  unsigned short* WvT = (unsigned short*)(ws + 28*MB);
  unsigned short* WoT = (unsigned short*)(ws + 30*MB);
  unsigned short* Qp  = (unsigned short*)(ws + 32*MB);  // projected Q (scaled*log2e), natural layout
  unsigned short* Kp  = (unsigned short*)(ws + 40*MB);  // projected K, natural layout
  unsigned short* VTb = (unsigned short*)(ws + 48*MB);  // projected V, [b][h][d][s]
  unsigned short* ctx = (unsigned short*)(ws + 56*MB);  // attention output, natural layout

  cast_qkv<<<dim3((BS*SEQ*DIM)/(256*8), 3), 256, 0, stream>>>(query, key, value, qb, kb, vb);
  wcast_t<<<dim3(DIM/32, DIM/32, 4), 256, 0, stream>>>(Wq, Wk, Wv, Wo, WqT, WkT, WvT, WoT);
  qkv_gemm<<<dim3(NWG, 3), 256, 0, stream>>>(qb, kb, vb, WqT, WkT, WvT, bq, bk, bv, Qp, Kp, VTb);
  attn<<<BS*NH*(SEQ/128), 512, 0, stream>>>(Qp, Kp, VTb, mask, gauss, ctx);
  out_gemm<<<NWG, 256, 0, stream>>>(ctx, WoT, bo, (float*)d_out);
}

// Round 17
// 102.458 us; speedup vs baseline: 2.5151x; 1.1033x over previous
//
#include <hip/hip_runtime.h>
#include <stdint.h>

#define BS 4
#define SEQ 1024
#define DIM 1024
#define NH 16
#define DH 64
#define MROWS (BS*SEQ)   // 4096

#define MT 128
#define NT 128
#define KT 32
#define NBM (MROWS/MT)   // 32
#define NBN (DIM/NT)     // 8
#define NWG (NBM*NBN)    // 256
#define NKT (DIM/KT)     // 32

typedef __attribute__((ext_vector_type(8))) short bf16x8;
typedef __attribute__((ext_vector_type(4))) float f32x4;
typedef __attribute__((ext_vector_type(8))) unsigned short ushort8;
typedef __attribute__((ext_vector_type(4))) float float4v;
typedef __attribute__((ext_vector_type(4))) int int4v;
typedef __attribute__((ext_vector_type(2))) unsigned int uint32x2;

__device__ __forceinline__ unsigned short f2bf(float x) {
  union { float f; uint32_t u; } a; a.f = x;
  uint32_t r = (a.u + 0x7FFFu + ((a.u >> 16) & 1u)) >> 16;  // RNE
  return (unsigned short)r;
}

// packed f32x2 -> bf16x2 (lo = first arg); no builtin on gfx950 -> inline asm (T12)
__device__ __forceinline__ uint32_t cvtpk_bf16(float lo, float hi) {
  uint32_t d;
  asm("v_cvt_pk_bf16_f32 %0, %1, %2" : "=v"(d) : "v"(lo), "v"(hi));
  return d;
}

// raw 2^x (softmax runs in log2 domain; log2e folded into Q scale upstream)
__device__ __forceinline__ float exp2a(float x) {
  float r;
  asm("v_exp_f32 %0, %1" : "=v"(r) : "v"(x));
  return r;
}

typedef const void __attribute__((address_space(1)))* gvp;
typedef void __attribute__((address_space(3)))* lvp;
__device__ __forceinline__ void gld_lds16(const void* g, void* l) {
  // async global->LDS, 16B/lane; LDS dest = wave-uniform base + lane*16
  __builtin_amdgcn_global_load_lds((gvp)g, (lvp)l, 16, 0, 0);
}

// ---------------- fp32 -> bf16 cast (query/key/value) ----------------
__global__ __launch_bounds__(256) void cast_qkv(
    const float* __restrict__ q, const float* __restrict__ k, const float* __restrict__ v,
    unsigned short* __restrict__ qo, unsigned short* __restrict__ ko, unsigned short* __restrict__ vo) {
  const float* s = blockIdx.y == 0 ? q : (blockIdx.y == 1 ? k : v);
  unsigned short* d = blockIdx.y == 0 ? qo : (blockIdx.y == 1 ? ko : vo);
  size_t i = ((size_t)blockIdx.x * 256 + threadIdx.x) * 8;
  float4v x0 = *(const float4v*)(s + i);
  float4v x1 = *(const float4v*)(s + i + 4);
  ushort8 r;
  r[0]=f2bf(x0[0]); r[1]=f2bf(x0[1]); r[2]=f2bf(x0[2]); r[3]=f2bf(x0[3]);
  r[4]=f2bf(x1[0]); r[5]=f2bf(x1[1]); r[6]=f2bf(x1[2]); r[7]=f2bf(x1[3]);
  *(ushort8*)(d + i) = r;
}

// ---------------- weight cast + transpose: WT[n][k] = bf16(W[k][n]) ----------------
__global__ __launch_bounds__(256) void wcast_t(
    const float* __restrict__ w0, const float* __restrict__ w1,
    const float* __restrict__ w2, const float* __restrict__ w3,
    unsigned short* __restrict__ t0, unsigned short* __restrict__ t1,
    unsigned short* __restrict__ t2, unsigned short* __restrict__ t3) {
  __shared__ float tile[32][33];
  const float* W = blockIdx.z == 0 ? w0 : blockIdx.z == 1 ? w1 : blockIdx.z == 2 ? w2 : w3;
  unsigned short* T = blockIdx.z == 0 ? t0 : blockIdx.z == 1 ? t1 : blockIdx.z == 2 ? t2 : t3;
  int tx = threadIdx.x & 31, ty = threadIdx.x >> 5;   // 32 x 8
  int bx = blockIdx.x, by = blockIdx.y;
#pragma unroll
  for (int j = 0; j < 4; j++)
    tile[ty + 8*j][tx] = W[(size_t)(by*32 + ty + 8*j)*DIM + bx*32 + tx];
  __syncthreads();
#pragma unroll
  for (int j = 0; j < 4; j++)
    T[(size_t)(bx*32 + ty + 8*j)*DIM + by*32 + tx] = f2bf(tile[tx][ty + 8*j]);
}

// ---------------- GEMM core: 128x128 tile, TRIPLE-buffered counted-vmcnt pipeline ----------------
// R16 diagnosis: at this shape each CU runs one block from each of 3 z-planes ->
// per-XCD working set 9MB > 4MB L2 -> stage loads land at L3 latency (~500cyc),
// and __syncthreads' implicit vmcnt(0) drained that EVERY iter (~450cyc/iter gap
// vs m97@4096^3). Fix: depth-2 prefetch (stage kt+2 at iter kt, 3 LDS buffers,
// cover = 2 iter bodies > L3 latency) + counted s_waitcnt vmcnt(4) (own stage(kt)
// done, stage(kt+1) stays in flight - never drains fresh loads) + bare s_barrier.
// Race check: (1) data-ready: all waves pass vmcnt(4)->barrier before any reads
// buf_kt; (2) overwrite: stage(kt+2) targets the buffer read at kt-1, issued
// AFTER the kt barrier which follows all kt-1 reads. Last iter uses vmcnt(0)
// (only 4 ops outstanding there - counted form would pass without waiting).
// MODE 0: bf16 out, (acc+bias)*scale; MODE 2: bf16 VT[b][h][d][s] packed b64;
// MODE 3: f32 out.
template<int MODE>
__device__ __forceinline__ void gemm_core(
    unsigned short* lds,
    const unsigned short* __restrict__ A, const unsigned short* __restrict__ BT,
    const float* __restrict__ bias, void* __restrict__ outp, float scale) {
  unsigned short* Abase = lds;                 // 3 x MT*KT
  unsigned short* Bbase = lds + 3*MT*KT;       // 3 x NT*KT
  int id = blockIdx.x;
  int sw = (id & 7) * (NWG/8) + (id >> 3);     // XCD swizzle (bijective, 256%8==0)
  int bn = sw & (NBN-1), bm = sw >> 3;         // bn-fast: XCD holds A-panels + B slice
  int tid = threadIdx.x, w = tid >> 6, l = tid & 63;
  int wr = w >> 1, wc = w & 1;
  int lr = l & 15, lg = l >> 4;

  auto stage = [&](int buf, int kt) {
    const unsigned short* a0 = A + (size_t)(bm*MT + w*32 + (l>>2))*DIM + kt*KT + (l&3)*8;
    gld_lds16(a0,          Abase + buf*MT*KT + (w*32)*KT);
    gld_lds16(a0 + 16*DIM, Abase + buf*MT*KT + (w*32 + 16)*KT);
    const unsigned short* b0 = BT + (size_t)(bn*NT + w*32 + (l>>2))*DIM + kt*KT + (l&3)*8;
    gld_lds16(b0,          Bbase + buf*NT*KT + (w*32)*KT);
    gld_lds16(b0 + 16*DIM, Bbase + buf*NT*KT + (w*32 + 16)*KT);
  };

  f32x4 acc[4][4] = {};
  stage(0, 0);
  stage(1, 1);
  int cur = 0;
  for (int kt = 0; kt < NKT; kt++) {
    if (kt < NKT-1) { asm volatile("s_waitcnt vmcnt(4)" ::: "memory"); }
    else            { asm volatile("s_waitcnt vmcnt(0)" ::: "memory"); }
    __builtin_amdgcn_s_barrier();
    __builtin_amdgcn_sched_barrier(0);
    if (kt + 2 < NKT) {
      int nb = cur + 2; if (nb >= 3) nb -= 3;
      stage(nb, kt + 2);
    }
    unsigned short* As = Abase + cur*MT*KT;
    unsigned short* Bs = Bbase + cur*NT*KT;
    bf16x8 af[4], bf_[4];
#pragma unroll
    for (int mi = 0; mi < 4; mi++)
      af[mi] = *(const bf16x8*)&As[(wr*64 + mi*16 + lr)*KT + lg*8];
#pragma unroll
    for (int ni = 0; ni < 4; ni++)
      bf_[ni] = *(const bf16x8*)&Bs[(wc*64 + ni*16 + lr)*KT + lg*8];
#pragma unroll
    for (int mi = 0; mi < 4; mi++)
#pragma unroll
      for (int ni = 0; ni < 4; ni++)
        acc[mi][ni] = __builtin_amdgcn_mfma_f32_16x16x32_bf16(af[mi], bf_[ni], acc[mi][ni], 0, 0, 0);
    cur = (cur + 1 == 3) ? 0 : cur + 1;
  }

  int row0 = bm*MT + wr*64;
  int col0 = bn*NT + wc*64;
#pragma unroll
  for (int ni = 0; ni < 4; ni++) {
    int col = col0 + ni*16 + lr;
    float bv = bias[col];
#pragma unroll
    for (int mi = 0; mi < 4; mi++) {
      if (MODE == 2) {
        // packed: 4 consecutive rows -> 4 consecutive s -> one b64 store
        int row = row0 + mi*16 + lg*4;
        int b = row >> 10, s = row & 1023, h = col >> 6, d = col & 63;
        uint32x2 e;
        e[0] = cvtpk_bf16(acc[mi][ni][0] + bv, acc[mi][ni][1] + bv);
        e[1] = cvtpk_bf16(acc[mi][ni][2] + bv, acc[mi][ni][3] + bv);
        *(uint32x2*)&((unsigned short*)outp)[(size_t)((b*NH + h)*DH + d)*SEQ + s] = e;
      } else {
#pragma unroll
        for (int r = 0; r < 4; r++) {
          int row = row0 + mi*16 + lg*4 + r;
          float val = acc[mi][ni][r] + bv;
          if (MODE == 0) {
            ((unsigned short*)outp)[(size_t)row*DIM + col] = f2bf(val * scale);
          } else {
            ((float*)outp)[(size_t)row*DIM + col] = val;
          }
        }
      }
    }
  }
}

__global__ __launch_bounds__(256) void qkv_gemm(
    const unsigned short* __restrict__ qb, const unsigned short* __restrict__ kb,
    const unsigned short* __restrict__ vb,
    const unsigned short* __restrict__ WqT, const unsigned short* __restrict__ WkT,
    const unsigned short* __restrict__ WvT,
    const float* __restrict__ bq, const float* __restrict__ bk, const float* __restrict__ bv,
    unsigned short* __restrict__ Qp, unsigned short* __restrict__ Kp,
    unsigned short* __restrict__ VT) {
  __shared__ __align__(16) unsigned short lds[3*(MT+NT)*KT];
  int z = blockIdx.y;
  // Q scale = 1/sqrt(64) * log2(e): softmax runs in exp2 domain downstream
  if (z == 0)      gemm_core<0>(lds, qb, WqT, bq, Qp, 0.18033688011112042f);
  else if (z == 1) gemm_core<0>(lds, kb, WkT, bk, Kp, 1.0f);
  else             gemm_core<2>(lds, vb, WvT, bv, VT, 1.0f);
}

__global__ __launch_bounds__(256) void out_gemm(
    const unsigned short* __restrict__ ctx, const unsigned short* __restrict__ WoT,
    const float* __restrict__ bo, float* __restrict__ out) {
  __shared__ __align__(16) unsigned short lds[3*(MT+NT)*KT];
  gemm_core<3>(lds, ctx, WoT, bo, out, 1.0f);
}

// ---------------- flash attention (R16 champion, unchanged) ----------------
// Block = 8 waves x 16 q-rows = 128 q-rows; grid 512 = exactly 2 blocks/CU ->
// 16 resident waves/CU. K+V zero-VGPR global_load_lds double buffers
// (XOR-swizzled, both-sides rule), swapped QK^T (lane owns q-row lr -> per-lane
// scalar softmax), exp2 domain, T13 defer-max, wave-local P slab with manual
// lgkmcnt fence, T5 setprio around MFMA clusters, single end-of-iter barrier.
__global__ __launch_bounds__(512, 4) void attn(
    const unsigned short* __restrict__ Qp, const unsigned short* __restrict__ Kp,
    const unsigned short* __restrict__ VT, const int* __restrict__ mask,
    const float* __restrict__ gauss, unsigned short* __restrict__ ctx) {
  __shared__ __align__(16) unsigned short Klds[2*64*64];  // 16KB double-buffered K tile
  __shared__ __align__(16) unsigned short Vlds[2*64*64];  // 16KB double-buffered V tile
  __shared__ __align__(16) unsigned short P[8][16][72];   // 18KB: per-wave slabs, padded
  __shared__ float gwl[SEQ];                              // mask-folded gauss weights
  int blk = blockIdx.x;
  int bh = blk & 63, qt = blk >> 6;        // head-major: head bh pinned to XCD bh%8
  int b = bh >> 4, h = bh & 15;
  int tid = threadIdx.x, w = tid >> 6, l = tid & 63;
  int lr = l & 15, lg = l >> 4;
  int q0 = qt*128 + w*16;                  // 8 waves cover 128 q-rows

  // ---- stash mask-folded gauss row in LDS (512 threads x 2 elems) ----
  {
    int i2 = tid * 2;
    gwl[i2]     = mask[b*SEQ + i2]     ? gauss[b*SEQ + i2]     + 1e-10f : 0.f;
    gwl[i2 + 1] = mask[b*SEQ + i2 + 1] ? gauss[b*SEQ + i2 + 1] + 1e-10f : 0.f;
  }

  const unsigned short* Qb = Qp + (size_t)(b*SEQ + q0 + lr)*DIM + h*DH + lg*8;
  bf16x8 aq0 = *(const bf16x8*)Qb;
  bf16x8 aq1 = *(const bf16x8*)(Qb + 32);

  float m_ = -1e30f, l_ = 0.f;             // per-lane scalars (q = lr), log2 domain
  f32x4 cacc[4] = {};                      // O^T[d = dt*16+lg*4+r][q = lr]

  const unsigned short* Krow0 = Kp + (size_t)(b*SEQ)*DIM + h*DH;   // key-rows, stride DIM
  const unsigned short* Vrow0 = VT + (size_t)((b*NH + h)*DH)*SEQ;  // d-rows, stride SEQ

  // staging geometry: per instr, lane l covers row (l>>3), 16B slot (l&7);
  // source slot pre-swizzled by row&7 (both-sides swizzle rule). 8 waves x
  // 8 rows = 64-row tile: exactly one gld_lds16 per wave per buffer.
  int srow = l >> 3;
  int scol = ((l & 7) ^ srow) * 8;
  auto stageK = [&](int buf, int key0) {
    gld_lds16(Krow0 + (size_t)(key0 + w*8 + srow)*DIM + scol, Klds + buf*64*64 + (w*8)*64);
  };
  auto stageV = [&](int buf, int key0) {
    gld_lds16(Vrow0 + (size_t)(w*8 + srow)*SEQ + key0 + scol, Vlds + buf*64*64 + (w*8)*64);
  };

  stageK(0, 0);
  stageV(0, 0);
  __syncthreads();   // gwl + K[0] + V[0] ready
  int buf = 0;
  int rx = lr & 7;   // swizzle index: (row&7) for all rows read below
  for (int kt = 0; kt < 16; kt++) {
    int key0 = kt*64;
    // ---- issue next K+V stages (async DMA, zero VGPR; drained by end-of-iter barrier) ----
    if (kt < 15) { stageK(buf ^ 1, key0 + 64); stageV(buf ^ 1, key0 + 64); }
    // ---- S^T = mfma(K, Q) from LDS (swizzled read): sa[nf][r] = S[key][q=lr] ----
    const unsigned short* Kt = Klds + buf*64*64;
    f32x4 sa[4] = {};
    __builtin_amdgcn_s_setprio(1);
#pragma unroll
    for (int nf = 0; nf < 4; nf++) {
      int r1 = nf*16 + lr;
      bf16x8 k0 = *(const bf16x8*)&Kt[r1*64 + ((lg       ^ rx) * 8)];
      bf16x8 k1 = *(const bf16x8*)&Kt[r1*64 + (((lg + 4) ^ rx) * 8)];
      sa[nf] = __builtin_amdgcn_mfma_f32_16x16x32_bf16(k0, aq0, sa[nf], 0, 0, 0);
      sa[nf] = __builtin_amdgcn_mfma_f32_16x16x32_bf16(k1, aq1, sa[nf], 0, 0, 0);
    }
    __builtin_amdgcn_s_setprio(0);
    // ---- V fragments from LDS (swizzled; ~120cyc, issued before softmax) ----
    const unsigned short* Vt = Vlds + buf*64*64;
    bf16x8 vf[4][2];
#pragma unroll
    for (int dt = 0; dt < 4; dt++) {
      int r2 = dt*16 + lr;
      vf[dt][0] = *(const bf16x8*)&Vt[r2*64 + ((lg       ^ rx) * 8)];
      vf[dt][1] = *(const bf16x8*)&Vt[r2*64 + (((lg + 4) ^ rx) * 8)];
    }
    // ---- online softmax in exp2 domain; tree max; T13 defer-max ----
    float t0 = fmaxf(fmaxf(sa[0][0], sa[0][1]), fmaxf(sa[0][2], sa[0][3]));
    float t1 = fmaxf(fmaxf(sa[1][0], sa[1][1]), fmaxf(sa[1][2], sa[1][3]));
    float t2 = fmaxf(fmaxf(sa[2][0], sa[2][1]), fmaxf(sa[2][2], sa[2][3]));
    float t3 = fmaxf(fmaxf(sa[3][0], sa[3][1]), fmaxf(sa[3][2], sa[3][3]));
    float mx = fmaxf(fmaxf(t0, t1), fmaxf(t2, t3));
    mx = fmaxf(mx, __shfl_xor(mx, 16));
    mx = fmaxf(mx, __shfl_xor(mx, 32));
    if (!__all(mx - m_ <= 8.0f)) {         // rescale only on real max growth
      float mn = fmaxf(m_, mx);
      float alpha = exp2a(m_ - mn);
      m_ = mn;
      l_ *= alpha;
#pragma unroll
      for (int dt = 0; dt < 4; dt++)
#pragma unroll
        for (int r = 0; r < 4; r++) cacc[dt][r] *= alpha;
    }
    float rsn[4];
    uint32_t u[4][2];
#pragma unroll
    for (int nf = 0; nf < 4; nf++) {
      float4v g = *(const float4v*)&gwl[key0 + nf*16 + lg*4];   // broadcast LDS read
      float p0 = exp2a(sa[nf][0] - m_) * g[0];
      float p1 = exp2a(sa[nf][1] - m_) * g[1];
      float p2 = exp2a(sa[nf][2] - m_) * g[2];
      float p3 = exp2a(sa[nf][3] - m_) * g[3];
      rsn[nf] = (p0 + p1) + (p2 + p3);
      u[nf][0] = cvtpk_bf16(p0, p1);
      u[nf][1] = cvtpk_bf16(p2, p3);
    }
    float rs = (rsn[0] + rsn[1]) + (rsn[2] + rsn[3]);
    rs += __shfl_xor(rs, 16);
    rs += __shfl_xor(rs, 32);
    l_ += rs;
    // ---- P[q=lr][key]: 4x ds_write_b64 into wave-local slab ----
#pragma unroll
    for (int nf = 0; nf < 4; nf++) {
      uint32x2 uu; uu[0] = u[nf][0]; uu[1] = u[nf][1];
      *(uint32x2*)&P[w][lr][nf*16 + lg*4] = uu;
    }
    asm volatile("s_waitcnt lgkmcnt(0)" ::: "memory");
    __builtin_amdgcn_sched_barrier(0);
    bf16x8 ap0 = *(const bf16x8*)&P[w][lr][lg*8];        // B-frag: keys 0..31
    bf16x8 ap1 = *(const bf16x8*)&P[w][lr][32 + lg*8];   // B-frag: keys 32..63
    // ---- O^T += mfma(V^T, P) ----
    __builtin_amdgcn_s_setprio(1);
#pragma unroll
    for (int dt = 0; dt < 4; dt++) {
      cacc[dt] = __builtin_amdgcn_mfma_f32_16x16x32_bf16(vf[dt][0], ap0, cacc[dt], 0, 0, 0);
      cacc[dt] = __builtin_amdgcn_mfma_f32_16x16x32_bf16(vf[dt][1], ap1, cacc[dt], 0, 0, 0);
    }
    __builtin_amdgcn_s_setprio(0);
    __syncthreads();   // dbuf swap: waves done reading K[t],V[t]; next stages drain here
    buf ^= 1;
  }

  // ---- epilogue: normalize, pack pairs, 4x b64 stores per lane ----
  float inv = 1.0f / l_;
  size_t row = (size_t)(b*SEQ + q0 + lr)*DIM + h*DH;
#pragma unroll
  for (int dt = 0; dt < 4; dt++) {
    uint32x2 e;
    e[0] = cvtpk_bf16(cacc[dt][0]*inv, cacc[dt][1]*inv);
    e[1] = cvtpk_bf16(cacc[dt][2]*inv, cacc[dt][3]*inv);
    *(uint32x2*)&ctx[row + dt*16 + lg*4] = e;
  }
}

// ---------------- launch ----------------
extern "C" void kernel_launch(void* const* d_in, const int* in_sizes, int n_in,
                              void* d_out, int out_size, void* d_ws, size_t ws_size,
                              hipStream_t stream) {
  const float* query = (const float*)d_in[0];
  const float* key   = (const float*)d_in[1];
  const float* value = (const float*)d_in[2];
  const int*   mask  = (const int*)d_in[3];
  const float* gauss = (const float*)d_in[4];
  const float* Wq = (const float*)d_in[5];
  const float* bq = (const float*)d_in[6];
  const float* Wk = (const float*)d_in[7];
  const float* bk = (const float*)d_in[8];
  const float* Wv = (const float*)d_in[9];
  const float* bv = (const float*)d_in[10];
  const float* Wo = (const float*)d_in[11];
  const float* bo = (const float*)d_in[12];

  char* ws = (char*)d_ws;
  const size_t MB = 1024*1024;
  unsigned short* qb  = (unsigned short*)(ws + 0*MB);   // bf16 casts of inputs (8MB each)
  unsigned short* kb  = (unsigned short*)(ws + 8*MB);
  unsigned short* vb  = (unsigned short*)(ws + 16*MB);
  unsigned short* WqT = (unsigned short*)(ws + 24*MB);  // transposed bf16 weights (2MB each)
  unsigned short* WkT = (unsigned short*)(ws + 26*MB);
  unsigned short* WvT = (unsigned short*)(ws + 28*MB);
  unsigned short* WoT = (unsigned short*)(ws + 30*MB);
  unsigned short* Qp  = (unsigned short*)(ws + 32*MB);  // projected Q (scaled*log2e), natural layout
  unsigned short* Kp  = (unsigned short*)(ws + 40*MB);  // projected K, natural layout
  unsigned short* VTb = (unsigned short*)(ws + 48*MB);  // projected V, [b][h][d][s]
  unsigned short* ctx = (unsigned short*)(ws + 56*MB);  // attention output, natural layout

  cast_qkv<<<dim3((BS*SEQ*DIM)/(256*8), 3), 256, 0, stream>>>(query, key, value, qb, kb, vb);
  wcast_t<<<dim3(DIM/32, DIM/32, 4), 256, 0, stream>>>(Wq, Wk, Wv, Wo, WqT, WkT, WvT, WoT);
  qkv_gemm<<<dim3(NWG, 3), 256, 0, stream>>>(qb, kb, vb, WqT, WkT, WvT, bq, bk, bv, Qp, Kp, VTb);
  attn<<<BS*NH*(SEQ/128), 512, 0, stream>>>(Qp, Kp, VTb, mask, gauss, ctx);
  out_gemm<<<NWG, 256, 0, stream>>>(ctx, WoT, bo, (float*)d_out);
}